// Round 10
// baseline (565.975 us; speedup 1.0000x reference)
//
#include <hip/hip_runtime.h>
#include <hip/hip_fp16.h>
#include <stdint.h>

namespace {

constexpr int NN   = 100000;    // nodes per graph
constexpr int TN   = 2 * NN;    // nodes across both graphs
constexpr int NEDG = 1600000;   // edges per graph
constexpr int TE   = 2 * NEDG;  // 3.2M edges across both graphs
constexpr int NBAT = 512;       // graphs per batch
constexpr int NSEG = 33;        // piecewise-linear segments of edge MLP (32 breakpoints)

// coarse partition: 256 dst-nodes per coarse bucket, fixed-capacity scratch
constexpr int NC     = 782;     // ceil(TN / 256)
constexpr int TILE   = 4096;    // edges per partition block (16 per thread)
constexpr int ABLK   = (TE + TILE - 1) / TILE;  // 782
constexpr int ENTCAP = 5120;    // bucket capacity (mean 4096, +16 sigma)

// persistent conv grids: 2048 blocks x 4 waves = 8192 waves (8 blocks/CU exact)
constexpr int CONVBLK = 2048;

// half2 LDS strides for the conv edge tables (16B-aligned for b128/b64 reads;
// stride*4 % 16 == 0, and stride mod 32 != 0 spreads the random seg id g
// across bank offsets)
constexpr int S1H = 20;  // conv1: 16 half2 (32 feat) + 4 pad
constexpr int S2H = 36;  // conv2: 32 half2 (64 feat) + 4 pad

// table layout (floats): bp[32] | d1[NSEG*32] | c1[NSEG*32] | per-enc {d2[NSEG*64], c2[NSEG*64]} x2
constexpr int TAB_BP = 0;
constexpr int TAB_D1 = 32;
constexpr int TAB_C1 = TAB_D1 + NSEG * 32;
constexpr int TAB_E2 = TAB_C1 + NSEG * 32;
constexpr int TAB_TOTAL = TAB_E2 + 4 * NSEG * 64;

__device__ __forceinline__ float relu_(float x) { return fmaxf(x, 0.0f); }

__device__ __forceinline__ float4 shfl_xor4(float4 v, int m) {
  return make_float4(__shfl_xor(v.x, m), __shfl_xor(v.y, m),
                     __shfl_xor(v.z, m), __shfl_xor(v.w, m));
}

__device__ __forceinline__ __half2 bch(int u) {
  return *reinterpret_cast<__half2*>(&u);
}
__device__ __forceinline__ int f2h2(float a, float b) {
  __half2 h = __floats2half2_rn(a, b);
  return *reinterpret_cast<int*>(&h);
}

// ---------------------------------------------------------------------------
// Precompute piecewise-linear tables for e(a) = relu(a*W1+b1)@W2+b2 and the
// folded e2(a) = e(a)@linW + linb. Exact reassociation of the reference math.
// Also zeroes gcur/psum (memset dispatches folded in; stream-ordered).
// ---------------------------------------------------------------------------
__global__ void build_tables(const float* __restrict__ eW1, const float* __restrict__ eb1,
                             const float* __restrict__ eW2, const float* __restrict__ eb2,
                             const float* __restrict__ sLW, const float* __restrict__ sLb,
                             const float* __restrict__ gLW, const float* __restrict__ gLb,
                             float* __restrict__ tabs,
                             int* __restrict__ gcur, float* __restrict__ psum) {
  __shared__ float traw[32];
  __shared__ float ts[32];
  __shared__ float dt[NSEG * 32];
  __shared__ float ct[NSEG * 32];
  int tid = threadIdx.x;
  // ---- folded memsets ----
  for (int i = tid; i < NC; i += blockDim.x) gcur[i] = 0;
  {
    float4* p4 = (float4*)psum;
    for (int i = tid; i < 2 * NBAT * 64 / 4; i += blockDim.x)
      p4[i] = make_float4(0.f, 0.f, 0.f, 0.f);
  }
  if (tid < 32) {
    float w = eW1[tid], b = eb1[tid];
    traw[tid] = (w != 0.0f) ? (-b / w) : 3.0e38f;
  }
  __syncthreads();
  if (tid < 32) {  // rank sort (stable for duplicates)
    float v = traw[tid];
    int r = 0;
    for (int j = 0; j < 32; ++j) {
      float u = traw[j];
      r += (u < v) || (u == v && j < tid);
    }
    ts[r] = v;
  }
  __syncthreads();
  if (tid < 32) tabs[TAB_BP + tid] = ts[tid];
  for (int idx = tid; idx < NSEG * 32; idx += blockDim.x) {
    int s = idx >> 5, j = idx & 31;
    float a;  // representative point strictly inside segment s: (ts[s-1], ts[s]]
    if (s == 0)            a = ts[0] - 1.0f;
    else if (s == NSEG - 1) a = ts[31] + 1.0f;
    else                   a = 0.5f * ts[s - 1] + 0.5f * ts[s];
    float d = 0.0f, c = 0.0f;
    for (int i = 0; i < 32; ++i) {
      float w = eW1[i], b = eb1[i];
      if (fmaf(a, w, b) > 0.0f) {
        float w2 = eW2[i * 32 + j];
        d = fmaf(w, w2, d);
        c = fmaf(b, w2, c);
      }
    }
    c += eb2[j];
    dt[idx] = d; ct[idx] = c;
    tabs[TAB_D1 + idx] = d;
    tabs[TAB_C1 + idx] = c;
  }
  __syncthreads();
  for (int idx = tid; idx < NSEG * 64; idx += blockDim.x) {
    int s = idx >> 6, k = idx & 63;
    float ds = 0.f, cs = 0.f, dg = 0.f, cg = 0.f;
    for (int j = 0; j < 32; ++j) {
      float dv = dt[s * 32 + j], cv = ct[s * 32 + j];
      float ws = sLW[j * 64 + k], wg = gLW[j * 64 + k];
      ds = fmaf(dv, ws, ds); cs = fmaf(cv, ws, cs);
      dg = fmaf(dv, wg, dg); cg = fmaf(cv, wg, cg);
    }
    cs += sLb[k]; cg += gLb[k];
    tabs[TAB_E2 + idx]                 = ds;
    tabs[TAB_E2 + NSEG * 64 + idx]     = cs;
    tabs[TAB_E2 + 2 * NSEG * 64 + idx] = dg;
    tabs[TAB_E2 + 3 * NSEG * 64 + idx] = cg;
  }
}

// ---------------------------------------------------------------------------
// Fused front: three INDEPENDENT jobs in one launch (block-range dispatch).
// R8 lesson: direct per-edge global scatter pays ~64B/edge write-allocate;
// the LDS staging here converts it into semi-contiguous bucket runs.
// ---------------------------------------------------------------------------
__global__ __launch_bounds__(256) void fused_front(
    const int* __restrict__ names_s, const int* __restrict__ names_g,
    const float* __restrict__ idW1, const float* __restrict__ idb1,
    const float* __restrict__ idW2, const float* __restrict__ idb2,
    const int* __restrict__ src_s, const int* __restrict__ dst_s, const float* __restrict__ attr_s,
    const int* __restrict__ src_g, const int* __restrict__ dst_g, const float* __restrict__ attr_g,
    const int* __restrict__ bat_s, const int* __restrict__ bat_g,
    const float* __restrict__ tabs,
    __half* __restrict__ x0h,
    int* __restrict__ gcur, int2* __restrict__ part,
    int* __restrict__ start_s, int* __restrict__ start_g) {
  __shared__ int hist[NC];
  __shared__ int lofs[NC];
  __shared__ int lcur[NC];
  __shared__ int2 sorted[TILE];
  __shared__ int addr[TILE];
  __shared__ int scanbuf[256];
  __shared__ float bp[32];
  int t = threadIdx.x;
  if (blockIdx.x < ABLK) {
    // ---- coarse partition tile ----
    if (t < 32) bp[t] = tabs[TAB_BP + t];
    for (int i = t; i < NC; i += 256) hist[i] = 0;
    __syncthreads();
    int base = blockIdx.x * TILE;
#pragma unroll
    for (int j = 0; j < 16; ++j) {
      int i = base + j * 256 + t;
      if (i < TE) {
        int d = (i < NEDG) ? dst_s[i] : (dst_g[i - NEDG] + NN);
        atomicAdd(&hist[d >> 8], 1);
      }
    }
    __syncthreads();
    int loc[4];
    int sum = 0;
#pragma unroll
    for (int j = 0; j < 4; ++j) {
      int b = t * 4 + j;
      int v = (b < NC) ? hist[b] : 0;
      loc[j] = sum; sum += v;
    }
    scanbuf[t] = sum;
    __syncthreads();
    for (int st = 1; st < 256; st <<= 1) {
      int u = (t >= st) ? scanbuf[t - st] : 0;
      __syncthreads();
      scanbuf[t] += u;
      __syncthreads();
    }
    int texcl = scanbuf[t] - sum;
#pragma unroll
    for (int j = 0; j < 4; ++j) {
      int b = t * 4 + j;
      if (b < NC) { lofs[b] = texcl + loc[j]; lcur[b] = 0; }
    }
    __syncthreads();
    // reserve space in each bucket's fixed-capacity region
    for (int b = t; b < NC; b += 256) {
      int c = hist[b];
      hist[b] = c ? atomicAdd(&gcur[b], c) : 0;
    }
    __syncthreads();
#pragma unroll
    for (int j = 0; j < 16; ++j) {
      int i = base + j * 256 + t;
      if (i < TE) {
        int sl, d; float a;
        if (i < NEDG) { sl = src_s[i]; d = dst_s[i]; a = attr_s[i]; }
        else { int k = i - NEDG; sl = src_g[k]; d = dst_g[k] + NN; a = attr_g[k]; }
        int seg = 0;
#pragma unroll
        for (int q = 0; q < 32; ++q) seg += (bp[q] < a);
        int c = d >> 8;
        int r = atomicAdd(&lcur[c], 1);
        int s = lofs[c] + r;
        sorted[s] = make_int2(sl | ((d & 255) << 17) | (seg << 25), __float_as_int(a));
        addr[s] = c * ENTCAP + hist[c] + r;
      }
    }
    __syncthreads();
    int tot = (base + TILE <= TE) ? TILE : (TE - base);
    for (int s = t; s < tot; s += 256) part[addr[s]] = sorted[s];
  } else if (blockIdx.x < ABLK + 782) {
    // ---- node embed (both graphs, fp16 shadow only; self term read as fp16) ----
    int n = (blockIdx.x - ABLK) * 256 + t;
    if (n >= TN) return;
    int name = (n < NN) ? names_s[n] : names_g[n - NN];
    float norm = ((float)name + 2.0f) / 281474976710655.0f;
    norm = fminf(fmaxf(norm, 0.0f), 1.0f);
    float h[32];
#pragma unroll
    for (int i = 0; i < 32; ++i) h[i] = relu_(fmaf(norm, idW1[i], idb1[i]));
    int2* outh = (int2*)(x0h + (size_t)n * 32);
    for (int j0 = 0; j0 < 32; j0 += 4) {
      float a0 = idb2[j0], a1 = idb2[j0 + 1], a2 = idb2[j0 + 2], a3 = idb2[j0 + 3];
#pragma unroll
      for (int i = 0; i < 32; ++i) {
        float hv = h[i];
        a0 = fmaf(hv, idW2[i * 32 + j0],     a0);
        a1 = fmaf(hv, idW2[i * 32 + j0 + 1], a1);
        a2 = fmaf(hv, idW2[i * 32 + j0 + 2], a2);
        a3 = fmaf(hv, idW2[i * 32 + j0 + 3], a3);
      }
      outh[j0 >> 2] = make_int2(f2h2(a0, a1), f2h2(a2, a3));
    }
  } else {
    // ---- batch boundaries ----
    int blk = blockIdx.x - ABLK - 782;
    int half = blk >= 391;
    const int* bat = half ? bat_g : bat_s;
    int* start = half ? start_g : start_s;
    int i = (blk - half * 391) * 256 + t;
    if (i >= NN) return;
    int cur = bat[i];
    int prev = (i == 0) ? -1 : bat[i - 1];
    for (int b = prev + 1; b <= cur; ++b) start[b] = i;
    if (i == NN - 1) {
      for (int b = cur + 1; b <= NBAT; ++b) start[b] = NN;
    }
  }
}

// ---------------------------------------------------------------------------
// partition -> CSR with the coarse scan INLINED (one fewer launch).
// ---------------------------------------------------------------------------
__global__ __launch_bounds__(256) void partition_to_csr(
    const int* __restrict__ gcur,
    const int2* __restrict__ part,
    int* __restrict__ rowptr, int2* __restrict__ colattr) {
  __shared__ int2 outE[ENTCAP];  // 40 KB
  __shared__ int hist[256];
  __shared__ int cur[256];
  __shared__ int sc[256];
  int t = threadIdx.x, b = blockIdx.x;  // grid exact: NC
  // ---- inline exclusive scan: obase = sum_{i<b} min(gcur[i], ENTCAP) ----
  {
    int acc = 0;
    for (int i = t; i < b; i += 256) acc += min(gcur[i], ENTCAP);
    sc[t] = acc;
    __syncthreads();
    for (int st = 128; st > 0; st >>= 1) {
      if (t < st) sc[t] += sc[t + st];
      __syncthreads();
    }
  }
  int obase = sc[0];
  if (b == 0 && t == 0) rowptr[TN] = TE;
  __syncthreads();  // done reading sc; reuse below
  hist[t] = 0;
  __syncthreads();
  int cnt = min(gcur[b], ENTCAP);
  int ibase = b * ENTCAP;
  for (int i = t; i < cnt; i += 256)
    atomicAdd(&hist[(part[ibase + i].x >> 17) & 255], 1);
  __syncthreads();
  int v = hist[t];
  sc[t] = v;
  __syncthreads();
  for (int st = 1; st < 256; st <<= 1) {
    int u = (t >= st) ? sc[t - st] : 0;
    __syncthreads();
    sc[t] += u;
    __syncthreads();
  }
  int excl = sc[t] - v;
  int gnode = b * 256 + t;
  if (gnode < TN) rowptr[gnode] = obase + excl;
  cur[t] = excl;
  __syncthreads();
  for (int i = t; i < cnt; i += 256) {
    int2 e = part[ibase + i];
    int dl = (e.x >> 17) & 255;
    int srcn = e.x & 0x1FFFF;
    int seg = (e.x >> 25) & 63;
    int pos = atomicAdd(&cur[dl], 1);
    float af = __int_as_float(e.y);
    // conv format: src<2^17 | seg<<20; attr pre-packed as half2(a,a)
    // (bit-identical to the conv-side __floats2half2_rn it replaces)
    outE[pos] = make_int2(srcn | (seg << 20), f2h2(af, af));
  }
  __syncthreads();
  for (int i = t; i < cnt; i += 256) colattr[obase + i] = outE[i];
}

// ---------------------------------------------------------------------------
// GINE aggregation, PERSISTENT blocks, DEPTH-2 software pipeline:
//   rowptr loaded TWO nodes ahead; first-iteration colattr loaded ONE node
//   ahead (its address uses begN from the PREVIOUS body -- fixing R4, where
//   the prefetch address consumed a same-body rowptr load and exposed its
//   latency, VALUBusy 37%). Steady state: every address in the body comes
//   from registers produced a full body earlier; the per-node critical path
//   is just the gather. First k-iteration is peeled with exec-masked gathers
//   (no wasted traffic) + masked-fma accumulate; clamped colattr reads hit
//   real edge entries, so the masked path stays finite. Tail loop (deg>16,
//   ~43% of nodes) is byte-identical to the proven R2 body.
// ---------------------------------------------------------------------------
__device__ __forceinline__ void e1mm(int2 xv, unsigned p, int h0, __half2 az, float m,
                                     const __half2* dt2, const __half2* ct2, float4& A) {
  int g = (int)(p >> 20);
  int2 dv = *(const int2*)&dt2[g * S1H + h0];
  int2 cv = *(const int2*)&ct2[g * S1H + h0];
  __half2 v; float2 f;
  v = __hadd2(bch(xv.x), __hfma2(az, bch(dv.x), bch(cv.x)));
  f = __half22float2(v); A.x = fmaf(m, relu_(f.x), A.x); A.y = fmaf(m, relu_(f.y), A.y);
  v = __hadd2(bch(xv.y), __hfma2(az, bch(dv.y), bch(cv.y)));
  f = __half22float2(v); A.z = fmaf(m, relu_(f.x), A.z); A.w = fmaf(m, relu_(f.y), A.w);
}

__global__ __launch_bounds__(256) void conv1_dual(
    const __half* __restrict__ x0h,
    const int* __restrict__ rowptr, const int2* __restrict__ colattr,
    const float* __restrict__ tabs, float* __restrict__ hb) {
  __shared__ __half2 dt2[NSEG * S1H];
  __shared__ __half2 ct2[NSEG * S1H];
  for (int i = threadIdx.x; i < NSEG * 16; i += 256) {
    int s = i >> 4, j = i & 15;
    dt2[s * S1H + j] = __floats2half2_rn(tabs[TAB_D1 + s * 32 + 2 * j],
                                         tabs[TAB_D1 + s * 32 + 2 * j + 1]);
    ct2[s * S1H + j] = __floats2half2_rn(tabs[TAB_C1 + s * 32 + 2 * j],
                                         tabs[TAB_C1 + s * 32 + 2 * j + 1]);
  }
  __syncthreads();
  int lane = threadIdx.x & 63;
  int sub = lane & 7;        // 8 edges in flight (x2 unroll = 16)
  int f0  = (lane >> 3) * 4; // 4 features per lane
  int h0  = (lane >> 3) * 2; // half2 index
  constexpr int STR = 4 * CONVBLK;  // 8192 waves
  int n = blockIdx.x * 4 + (threadIdx.x >> 6);
  // pipeline prologue: rowptr for n and n+STR; colattr for n
  int begC = rowptr[n], endC = rowptr[n + 1];
  int begN = 0, endN = 0;
  if (n + STR < TN) { begN = rowptr[n + STR]; endN = rowptr[n + STR + 1]; }
  int2 c0 = colattr[min(begC + sub, TE - 1)];
  int2 c1 = colattr[min(begC + sub + 8, TE - 1)];
  for (; n < TN; n += STR) {
    // rowptr two ahead (consumed by NEXT body's colattr prefetch)
    int begNN = 0, endNN = 0;
    int n2 = n + 2 * STR;
    if (n2 < TN) { begNN = rowptr[n2]; endNN = rowptr[n2 + 1]; }
    // colattr one ahead (address from begN: produced LAST body)
    int2 cN0 = colattr[min(begN + sub, TE - 1)];
    int2 cN1 = colattr[min(begN + sub + 8, TE - 1)];
    const __half* xb = x0h + (n >= NN ? (size_t)NN * 32 : 0);
    int2 sv = make_int2(0, 0);
    if (sub == 0) sv = *(const int2*)(x0h + (size_t)n * 32 + f0);
    float4 acc = make_float4(0.f, 0.f, 0.f, 0.f);
    // peeled first iteration (covers deg <= 16): gathers start immediately
    {
      int k0 = begC + sub;
      bool v0 = k0 < endC, v1 = k0 + 8 < endC;
      unsigned p0 = (unsigned)c0.x, p1 = (unsigned)c1.x;
      int2 xv0 = make_int2(0, 0), xv1 = make_int2(0, 0);
      if (v0) xv0 = *(const int2*)(xb + (size_t)(p0 & 0xFFFFFu) * 32 + f0);
      if (v1) xv1 = *(const int2*)(xb + (size_t)(p1 & 0xFFFFFu) * 32 + f0);
      e1mm(xv0, p0, h0, bch(c0.y), v0 ? 1.f : 0.f, dt2, ct2, acc);
      e1mm(xv1, p1, h0, bch(c1.y), v1 ? 1.f : 0.f, dt2, ct2, acc);
    }
    // tail (deg > 16): proven R2 body
    for (int k = begC + 16 + sub; k < endC; k += 16) {
      int2 ca0 = colattr[k];
      int kb = k + 8;
      bool has1 = kb < endC;
      int2 ca1 = has1 ? colattr[kb] : ca0;
      unsigned p0 = (unsigned)ca0.x, p1 = (unsigned)ca1.x;
      int s0 = (int)(p0 & 0xFFFFFu), g0 = (int)(p0 >> 20);
      int s1 = (int)(p1 & 0xFFFFFu), g1 = (int)(p1 >> 20);
      __half2 az0 = bch(ca0.y);
      __half2 az1 = bch(ca1.y);
      int2 xv0 = *(const int2*)(xb + (size_t)s0 * 32 + f0);
      int2 xv1 = *(const int2*)(xb + (size_t)s1 * 32 + f0);
      int2 dv0 = *(const int2*)&dt2[g0 * S1H + h0];
      int2 cv0 = *(const int2*)&ct2[g0 * S1H + h0];
      __half2 v;
      float2 f;
      v = __hadd2(bch(xv0.x), __hfma2(az0, bch(dv0.x), bch(cv0.x)));
      f = __half22float2(v); acc.x += relu_(f.x); acc.y += relu_(f.y);
      v = __hadd2(bch(xv0.y), __hfma2(az0, bch(dv0.y), bch(cv0.y)));
      f = __half22float2(v); acc.z += relu_(f.x); acc.w += relu_(f.y);
      if (has1) {
        int2 dv1 = *(const int2*)&dt2[g1 * S1H + h0];
        int2 cv1 = *(const int2*)&ct2[g1 * S1H + h0];
        v = __hadd2(bch(xv1.x), __hfma2(az1, bch(dv1.x), bch(cv1.x)));
        f = __half22float2(v); acc.x += relu_(f.x); acc.y += relu_(f.y);
        v = __hadd2(bch(xv1.y), __hfma2(az1, bch(dv1.y), bch(cv1.y)));
        f = __half22float2(v); acc.z += relu_(f.x); acc.w += relu_(f.y);
      }
    }
#pragma unroll
    for (int m = 1; m < 8; m <<= 1) {
      float4 o = shfl_xor4(acc, m);
      acc.x += o.x; acc.y += o.y; acc.z += o.z; acc.w += o.w;
    }
    if (sub == 0) {
      float2 t0 = __half22float2(bch(sv.x)), t1 = __half22float2(bch(sv.y));
      *(float4*)(hb + (size_t)n * 32 + f0) =
          make_float4(t0.x + acc.x, t0.y + acc.y, t1.x + acc.z, t1.y + acc.w);
    }
    // rotate pipeline
    begC = begN; endC = endN;
    begN = begNN; endN = endNN;
    c0 = cN0; c1 = cN1;
  }
}

__device__ __forceinline__ void e2mm(int4 xv, unsigned p, int h0, __half2 az, float m,
                                     const __half2* dt2, const __half2* ct2,
                                     float4& A, float4& B) {
  int g = (int)(p >> 20);
  int4 dv = *(const int4*)&dt2[g * S2H + h0];
  int4 cv = *(const int4*)&ct2[g * S2H + h0];
  __half2 v; float2 f;
  v = __hadd2(bch(xv.x), __hfma2(az, bch(dv.x), bch(cv.x)));
  f = __half22float2(v); A.x = fmaf(m, relu_(f.x), A.x); A.y = fmaf(m, relu_(f.y), A.y);
  v = __hadd2(bch(xv.y), __hfma2(az, bch(dv.y), bch(cv.y)));
  f = __half22float2(v); A.z = fmaf(m, relu_(f.x), A.z); A.w = fmaf(m, relu_(f.y), A.w);
  v = __hadd2(bch(xv.z), __hfma2(az, bch(dv.z), bch(cv.z)));
  f = __half22float2(v); B.x = fmaf(m, relu_(f.x), B.x); B.y = fmaf(m, relu_(f.y), B.y);
  v = __hadd2(bch(xv.w), __hfma2(az, bch(dv.w), bch(cv.w)));
  f = __half22float2(v); B.z = fmaf(m, relu_(f.x), B.z); B.w = fmaf(m, relu_(f.y), B.w);
}

__global__ __launch_bounds__(256) void conv2_dual(
    const __half* __restrict__ x1h,
    const int* __restrict__ rowptr, const int2* __restrict__ colattr,
    const float* __restrict__ tabs, float* __restrict__ hb) {
  __shared__ __half2 dt2[NSEG * S2H];
  __shared__ __half2 ct2[NSEG * S2H];
  int halfg = blockIdx.x >= (CONVBLK / 2);  // blocks [0,1024): graph s; [1024,2048): graph g
  const float* d2 = tabs + TAB_E2 + (size_t)halfg * 2 * NSEG * 64;
  for (int i = threadIdx.x; i < NSEG * 32; i += 256) {
    int s = i >> 5, j = i & 31;
    dt2[s * S2H + j] = __floats2half2_rn(d2[s * 64 + 2 * j], d2[s * 64 + 2 * j + 1]);
    ct2[s * S2H + j] = __floats2half2_rn(d2[NSEG * 64 + s * 64 + 2 * j],
                                         d2[NSEG * 64 + s * 64 + 2 * j + 1]);
  }
  __syncthreads();
  const __half* xb = x1h + (size_t)halfg * NN * 64;  // src ids graph-local
  int lane = threadIdx.x & 63;
  int sub = lane & 7;        // 8 edges in flight (x2 unroll = 16)
  int f0  = (lane >> 3) * 8; // 8 features per lane
  int h0  = (lane >> 3) * 4; // half2 index
  constexpr int STR2 = 2 * CONVBLK;  // 4096 waves per half
  int wid = (blockIdx.x - halfg * (CONVBLK / 2)) * 4 + (threadIdx.x >> 6);
  int nlim = halfg * NN + NN;
  int n = halfg * NN + wid;
  // pipeline prologue
  int begC = rowptr[n], endC = rowptr[n + 1];
  int begN = 0, endN = 0;
  if (n + STR2 < nlim) { begN = rowptr[n + STR2]; endN = rowptr[n + STR2 + 1]; }
  int2 c0 = colattr[min(begC + sub, TE - 1)];
  int2 c1 = colattr[min(begC + sub + 8, TE - 1)];
  for (; n < nlim; n += STR2) {
    int begNN = 0, endNN = 0;
    int n2 = n + 2 * STR2;
    if (n2 < nlim) { begNN = rowptr[n2]; endNN = rowptr[n2 + 1]; }
    int2 cN0 = colattr[min(begN + sub, TE - 1)];
    int2 cN1 = colattr[min(begN + sub + 8, TE - 1)];
    int4 sv0 = make_int4(0, 0, 0, 0);
    if (sub == 0) sv0 = *(const int4*)(x1h + (size_t)n * 64 + f0);
    float4 accA = make_float4(0.f, 0.f, 0.f, 0.f);
    float4 accB = make_float4(0.f, 0.f, 0.f, 0.f);
    // peeled first iteration (deg <= 16 common case)
    {
      int k0 = begC + sub;
      bool v0 = k0 < endC, v1 = k0 + 8 < endC;
      unsigned p0 = (unsigned)c0.x, p1 = (unsigned)c1.x;
      int4 xv0 = make_int4(0, 0, 0, 0), xv1 = make_int4(0, 0, 0, 0);
      if (v0) xv0 = *(const int4*)(xb + (size_t)(p0 & 0xFFFFFu) * 64 + f0);
      if (v1) xv1 = *(const int4*)(xb + (size_t)(p1 & 0xFFFFFu) * 64 + f0);
      e2mm(xv0, p0, h0, bch(c0.y), v0 ? 1.f : 0.f, dt2, ct2, accA, accB);
      e2mm(xv1, p1, h0, bch(c1.y), v1 ? 1.f : 0.f, dt2, ct2, accA, accB);
    }
    // tail (deg > 16): proven R2 body
    for (int k = begC + 16 + sub; k < endC; k += 16) {
      int2 ca0 = colattr[k];
      int kb = k + 8;
      bool has1 = kb < endC;
      int2 ca1 = has1 ? colattr[kb] : ca0;
      unsigned p0 = (unsigned)ca0.x, p1 = (unsigned)ca1.x;
      int s0 = (int)(p0 & 0xFFFFFu), g0 = (int)(p0 >> 20);
      int s1 = (int)(p1 & 0xFFFFFu), g1 = (int)(p1 >> 20);
      __half2 az0 = bch(ca0.y);
      __half2 az1 = bch(ca1.y);
      int4 xv0 = *(const int4*)(xb + (size_t)s0 * 64 + f0);
      int4 xv1 = *(const int4*)(xb + (size_t)s1 * 64 + f0);
      int4 dv0 = *(const int4*)&dt2[g0 * S2H + h0];
      int4 cv0 = *(const int4*)&ct2[g0 * S2H + h0];
      __half2 v;
      float2 f;
      v = __hadd2(bch(xv0.x), __hfma2(az0, bch(dv0.x), bch(cv0.x)));
      f = __half22float2(v); accA.x += relu_(f.x); accA.y += relu_(f.y);
      v = __hadd2(bch(xv0.y), __hfma2(az0, bch(dv0.y), bch(cv0.y)));
      f = __half22float2(v); accA.z += relu_(f.x); accA.w += relu_(f.y);
      v = __hadd2(bch(xv0.z), __hfma2(az0, bch(dv0.z), bch(cv0.z)));
      f = __half22float2(v); accB.x += relu_(f.x); accB.y += relu_(f.y);
      v = __hadd2(bch(xv0.w), __hfma2(az0, bch(dv0.w), bch(cv0.w)));
      f = __half22float2(v); accB.z += relu_(f.x); accB.w += relu_(f.y);
      if (has1) {
        int4 dv1 = *(const int4*)&dt2[g1 * S2H + h0];
        int4 cv1 = *(const int4*)&ct2[g1 * S2H + h0];
        v = __hadd2(bch(xv1.x), __hfma2(az1, bch(dv1.x), bch(cv1.x)));
        f = __half22float2(v); accA.x += relu_(f.x); accA.y += relu_(f.y);
        v = __hadd2(bch(xv1.y), __hfma2(az1, bch(dv1.y), bch(cv1.y)));
        f = __half22float2(v); accA.z += relu_(f.x); accA.w += relu_(f.y);
        v = __hadd2(bch(xv1.z), __hfma2(az1, bch(dv1.z), bch(cv1.z)));
        f = __half22float2(v); accB.x += relu_(f.x); accB.y += relu_(f.y);
        v = __hadd2(bch(xv1.w), __hfma2(az1, bch(dv1.w), bch(cv1.w)));
        f = __half22float2(v); accB.z += relu_(f.x); accB.w += relu_(f.y);
      }
    }
#pragma unroll
    for (int m = 1; m < 8; m <<= 1) {
      float4 oA = shfl_xor4(accA, m);
      float4 oB = shfl_xor4(accB, m);
      accA.x += oA.x; accA.y += oA.y; accA.z += oA.z; accA.w += oA.w;
      accB.x += oB.x; accB.y += oB.y; accB.z += oB.z; accB.w += oB.w;
    }
    if (sub == 0) {
      float2 t0 = __half22float2(bch(sv0.x)), t1 = __half22float2(bch(sv0.y));
      float2 t2 = __half22float2(bch(sv0.z)), t3 = __half22float2(bch(sv0.w));
      float* op = hb + (size_t)n * 64 + f0;
      *(float4*)op       = make_float4(t0.x + accA.x, t0.y + accA.y, t1.x + accA.z, t1.y + accA.w);
      *(float4*)(op + 4) = make_float4(t2.x + accB.x, t2.y + accB.y, t3.x + accB.z, t3.y + accB.w);
    }
    // rotate pipeline
    begC = begN; endC = endN;
    begN = begNN; endN = endNN;
    c0 = cN0; c1 = cN1;
  }
}

// ---------------------------------------------------------------------------
// Per-node MLP2 (32 -> 64 -> 64) over BOTH graphs, fp16 shadow output ONLY.
// Register-tiled: thread owns 4 nodes x 4 features (16 independent chains).
// ---------------------------------------------------------------------------
__global__ __launch_bounds__(256) void mlp1_dual(
    const float* __restrict__ hin,
    const float* __restrict__ sW1, const float* __restrict__ sb1,
    const float* __restrict__ sW2, const float* __restrict__ sb2,
    const float* __restrict__ gW1, const float* __restrict__ gb1,
    const float* __restrict__ gW2, const float* __restrict__ gb2,
    __half* __restrict__ hout) {
  constexpr int IN = 32;
  __shared__ float hsT[IN][65];
  __shared__ float ysT[64][65];
  int base = blockIdx.x * 64;     // grid exact: TN/64 = 3125
  for (int idx = threadIdx.x; idx < 64 * IN; idx += 256) {
    int node = idx / IN, k = idx - node * IN;
    hsT[k][node] = hin[(size_t)(base + node) * IN + k];
  }
  __syncthreads();
  int nt = threadIdx.x >> 4, jx = threadIdx.x & 15;
  int n0 = nt * 4, f0 = jx * 4;
  bool isg = (base + n0) >= NN;
  const float* W1 = isg ? gW1 : sW1;
  const float* b1 = isg ? gb1 : sb1;
  const float* W2 = isg ? gW2 : sW2;
  const float* b2 = isg ? gb2 : sb2;
  float4 acc0, acc1, acc2, acc3;
  {
    const float4 b = *(const float4*)(b1 + f0);
    acc0 = b; acc1 = b; acc2 = b; acc3 = b;
  }
  for (int k = 0; k < IN; ++k) {
    const float4 h = *(const float4*)&hsT[k][n0];
    const float4 w = *(const float4*)(W1 + k * 64 + f0);
    acc0.x = fmaf(h.x, w.x, acc0.x); acc0.y = fmaf(h.x, w.y, acc0.y);
    acc0.z = fmaf(h.x, w.z, acc0.z); acc0.w = fmaf(h.x, w.w, acc0.w);
    acc1.x = fmaf(h.y, w.x, acc1.x); acc1.y = fmaf(h.y, w.y, acc1.y);
    acc1.z = fmaf(h.y, w.z, acc1.z); acc1.w = fmaf(h.y, w.w, acc1.w);
    acc2.x = fmaf(h.z, w.x, acc2.x); acc2.y = fmaf(h.z, w.y, acc2.y);
    acc2.z = fmaf(h.z, w.z, acc2.z); acc2.w = fmaf(h.z, w.w, acc2.w);
    acc3.x = fmaf(h.w, w.x, acc3.x); acc3.y = fmaf(h.w, w.y, acc3.y);
    acc3.z = fmaf(h.w, w.z, acc3.z); acc3.w = fmaf(h.w, w.w, acc3.w);
  }
  ysT[f0 + 0][n0 + 0] = relu_(acc0.x); ysT[f0 + 1][n0 + 0] = relu_(acc0.y);
  ysT[f0 + 2][n0 + 0] = relu_(acc0.z); ysT[f0 + 3][n0 + 0] = relu_(acc0.w);
  ysT[f0 + 0][n0 + 1] = relu_(acc1.x); ysT[f0 + 1][n0 + 1] = relu_(acc1.y);
  ysT[f0 + 2][n0 + 1] = relu_(acc1.z); ysT[f0 + 3][n0 + 1] = relu_(acc1.w);
  ysT[f0 + 0][n0 + 2] = relu_(acc2.x); ysT[f0 + 1][n0 + 2] = relu_(acc2.y);
  ysT[f0 + 2][n0 + 2] = relu_(acc2.z); ysT[f0 + 3][n0 + 2] = relu_(acc2.w);
  ysT[f0 + 0][n0 + 3] = relu_(acc3.x); ysT[f0 + 1][n0 + 3] = relu_(acc3.y);
  ysT[f0 + 2][n0 + 3] = relu_(acc3.z); ysT[f0 + 3][n0 + 3] = relu_(acc3.w);
  __syncthreads();
  {
    const float4 b = *(const float4*)(b2 + f0);
    acc0 = b; acc1 = b; acc2 = b; acc3 = b;
  }
  for (int k = 0; k < 64; ++k) {
    const float4 h = *(const float4*)&ysT[k][n0];
    const float4 w = *(const float4*)(W2 + k * 64 + f0);
    acc0.x = fmaf(h.x, w.x, acc0.x); acc0.y = fmaf(h.x, w.y, acc0.y);
    acc0.z = fmaf(h.x, w.z, acc0.z); acc0.w = fmaf(h.x, w.w, acc0.w);
    acc1.x = fmaf(h.y, w.x, acc1.x); acc1.y = fmaf(h.y, w.y, acc1.y);
    acc1.z = fmaf(h.y, w.z, acc1.z); acc1.w = fmaf(h.y, w.w, acc1.w);
    acc2.x = fmaf(h.z, w.x, acc2.x); acc2.y = fmaf(h.z, w.y, acc2.y);
    acc2.z = fmaf(h.z, w.z, acc2.z); acc2.w = fmaf(h.z, w.w, acc2.w);
    acc3.x = fmaf(h.w, w.x, acc3.x); acc3.y = fmaf(h.w, w.y, acc3.y);
    acc3.z = fmaf(h.w, w.z, acc3.z); acc3.w = fmaf(h.w, w.w, acc3.w);
  }
  float4 o;
  o = make_float4(relu_(acc0.x), relu_(acc0.y), relu_(acc0.z), relu_(acc0.w));
  *(int2*)(hout + (size_t)(base + n0 + 0) * 64 + f0) = make_int2(f2h2(o.x, o.y), f2h2(o.z, o.w));
  o = make_float4(relu_(acc1.x), relu_(acc1.y), relu_(acc1.z), relu_(acc1.w));
  *(int2*)(hout + (size_t)(base + n0 + 1) * 64 + f0) = make_int2(f2h2(o.x, o.y), f2h2(o.z, o.w));
  o = make_float4(relu_(acc2.x), relu_(acc2.y), relu_(acc2.z), relu_(acc2.w));
  *(int2*)(hout + (size_t)(base + n0 + 2) * 64 + f0) = make_int2(f2h2(o.x, o.y), f2h2(o.z, o.w));
  o = make_float4(relu_(acc3.x), relu_(acc3.y), relu_(acc3.z), relu_(acc3.w));
  *(int2*)(hout + (size_t)(base + n0 + 3) * 64 + f0) = make_int2(f2h2(o.x, o.y), f2h2(o.z, o.w));
}

// ---------------------------------------------------------------------------
// mlp2 + pool fused: outputs go to LDS, per-block run-length reduction over
// batch segments, ~300 fp32 atomics/block into psum (no x2 round-trip).
// ---------------------------------------------------------------------------
__global__ __launch_bounds__(256) void mlp2_pool_dual(
    const float* __restrict__ hin,
    const float* __restrict__ sW1, const float* __restrict__ sb1,
    const float* __restrict__ sW2, const float* __restrict__ sb2,
    const float* __restrict__ gW1, const float* __restrict__ gb1,
    const float* __restrict__ gW2, const float* __restrict__ gb2,
    const int* __restrict__ bat_s, const int* __restrict__ bat_g,
    float* __restrict__ psum) {
  constexpr int IN = 64;
  __shared__ float hsT[IN][65];
  __shared__ float ysT[64][65];
  __shared__ int pid[64];
  int base = blockIdx.x * 64;     // grid exact: TN/64 = 3125
  for (int idx = threadIdx.x; idx < 64 * IN; idx += 256) {
    int node = idx / IN, k = idx - node * IN;
    hsT[k][node] = hin[(size_t)(base + node) * IN + k];
  }
  if (threadIdx.x < 64) {
    int gb = base + threadIdx.x;
    pid[threadIdx.x] = (gb < NN) ? bat_s[gb] : (NBAT + bat_g[gb - NN]);
  }
  __syncthreads();
  int nt = threadIdx.x >> 4, jx = threadIdx.x & 15;
  int n0 = nt * 4, f0 = jx * 4;
  bool isg = (base + n0) >= NN;
  const float* W1 = isg ? gW1 : sW1;
  const float* b1 = isg ? gb1 : sb1;
  const float* W2 = isg ? gW2 : sW2;
  const float* b2 = isg ? gb2 : sb2;
  float4 acc0, acc1, acc2, acc3;
  {
    const float4 b = *(const float4*)(b1 + f0);
    acc0 = b; acc1 = b; acc2 = b; acc3 = b;
  }
  for (int k = 0; k < IN; ++k) {
    const float4 h = *(const float4*)&hsT[k][n0];
    const float4 w = *(const float4*)(W1 + k * 64 + f0);
    acc0.x = fmaf(h.x, w.x, acc0.x); acc0.y = fmaf(h.x, w.y, acc0.y);
    acc0.z = fmaf(h.x, w.z, acc0.z); acc0.w = fmaf(h.x, w.w, acc0.w);
    acc1.x = fmaf(h.y, w.x, acc1.x); acc1.y = fmaf(h.y, w.y, acc1.y);
    acc1.z = fmaf(h.y, w.z, acc1.z); acc1.w = fmaf(h.y, w.w, acc1.w);
    acc2.x = fmaf(h.z, w.x, acc2.x); acc2.y = fmaf(h.z, w.y, acc2.y);
    acc2.z = fmaf(h.z, w.z, acc2.z); acc2.w = fmaf(h.z, w.w, acc2.w);
    acc3.x = fmaf(h.w, w.x, acc3.x); acc3.y = fmaf(h.w, w.y, acc3.y);
    acc3.z = fmaf(h.w, w.z, acc3.z); acc3.w = fmaf(h.w, w.w, acc3.w);
  }
  ysT[f0 + 0][n0 + 0] = relu_(acc0.x); ysT[f0 + 1][n0 + 0] = relu_(acc0.y);
  ysT[f0 + 2][n0 + 0] = relu_(acc0.z); ysT[f0 + 3][n0 + 0] = relu_(acc0.w);
  ysT[f0 + 0][n0 + 1] = relu_(acc1.x); ysT[f0 + 1][n0 + 1] = relu_(acc1.y);
  ysT[f0 + 2][n0 + 1] = relu_(acc1.z); ysT[f0 + 3][n0 + 1] = relu_(acc1.w);
  ysT[f0 + 0][n0 + 2] = relu_(acc2.x); ysT[f0 + 1][n0 + 2] = relu_(acc2.y);
  ysT[f0 + 2][n0 + 2] = relu_(acc2.z); ysT[f0 + 3][n0 + 2] = relu_(acc2.w);
  ysT[f0 + 0][n0 + 3] = relu_(acc3.x); ysT[f0 + 1][n0 + 3] = relu_(acc3.y);
  ysT[f0 + 2][n0 + 3] = relu_(acc3.z); ysT[f0 + 3][n0 + 3] = relu_(acc3.w);
  __syncthreads();
  {
    const float4 b = *(const float4*)(b2 + f0);
    acc0 = b; acc1 = b; acc2 = b; acc3 = b;
  }
  for (int k = 0; k < 64; ++k) {
    const float4 h = *(const float4*)&ysT[k][n0];
    const float4 w = *(const float4*)(W2 + k * 64 + f0);
    acc0.x = fmaf(h.x, w.x, acc0.x); acc0.y = fmaf(h.x, w.y, acc0.y);
    acc0.z = fmaf(h.x, w.z, acc0.z); acc0.w = fmaf(h.x, w.w, acc0.w);
    acc1.x = fmaf(h.y, w.x, acc1.x); acc1.y = fmaf(h.y, w.y, acc1.y);
    acc1.z = fmaf(h.y, w.z, acc1.z); acc1.w = fmaf(h.y, w.w, acc1.w);
    acc2.x = fmaf(h.z, w.x, acc2.x); acc2.y = fmaf(h.z, w.y, acc2.y);
    acc2.z = fmaf(h.z, w.z, acc2.z); acc2.w = fmaf(h.z, w.w, acc2.w);
    acc3.x = fmaf(h.w, w.x, acc3.x); acc3.y = fmaf(h.w, w.y, acc3.y);
    acc3.z = fmaf(h.w, w.z, acc3.z); acc3.w = fmaf(h.w, w.w, acc3.w);
  }
  __syncthreads();  // all reads of ysT done; reuse it for outputs [f][node]
  ysT[f0 + 0][n0 + 0] = relu_(acc0.x); ysT[f0 + 1][n0 + 0] = relu_(acc0.y);
  ysT[f0 + 2][n0 + 0] = relu_(acc0.z); ysT[f0 + 3][n0 + 0] = relu_(acc0.w);
  ysT[f0 + 0][n0 + 1] = relu_(acc1.x); ysT[f0 + 1][n0 + 1] = relu_(acc1.y);
  ysT[f0 + 2][n0 + 1] = relu_(acc1.z); ysT[f0 + 3][n0 + 1] = relu_(acc1.w);
  ysT[f0 + 0][n0 + 2] = relu_(acc2.x); ysT[f0 + 1][n0 + 2] = relu_(acc2.y);
  ysT[f0 + 2][n0 + 2] = relu_(acc2.z); ysT[f0 + 3][n0 + 2] = relu_(acc2.w);
  ysT[f0 + 0][n0 + 3] = relu_(acc3.x); ysT[f0 + 1][n0 + 3] = relu_(acc3.y);
  ysT[f0 + 2][n0 + 3] = relu_(acc3.z); ysT[f0 + 3][n0 + 3] = relu_(acc3.w);
  __syncthreads();
  // pool: thread (c, f) sums nodes [c*16, c*16+16) of feature f, flushing
  // per batch-segment run (nodes are sorted by batch within each graph)
  int c = threadIdx.x >> 6, f = threadIdx.x & 63;
  int cur = pid[c * 16];
  float run = 0.0f;
  for (int i = 0; i < 16; ++i) {
    int nx = c * 16 + i;
    int p = pid[nx];
    if (p != cur) { atomicAdd(&psum[(size_t)cur * 64 + f], run); run = 0.0f; cur = p; }
    run += ysT[f][nx];
  }
  atomicAdd(&psum[(size_t)cur * 64 + f], run);
}

// ---------------------------------------------------------------------------
// regressor: out[b] = relu([s_mean|g_mean|depth] @ rW1 + rb1) @ rW2 + rb2
// ---------------------------------------------------------------------------
__global__ __launch_bounds__(256) void regressor16(
    const float* __restrict__ psum,
    const int* __restrict__ start_s, const int* __restrict__ start_g,
    const float* __restrict__ depth,
    const float* __restrict__ W1, const float* __restrict__ b1,
    const float* __restrict__ W2, const float* __restrict__ b2,
    float* __restrict__ out) {
  __shared__ float zs[16][132];   // [row][k], k in [0,129)
  __shared__ float ys[64][17];
  __shared__ float inv_s[16], inv_g[16];
  int base = blockIdx.x * 16;     // grid 32 blocks x 16 rows = 512 exact
  if (threadIdx.x < 16) {
    int b = base + threadIdx.x;
    inv_s[threadIdx.x] = 1.0f / fmaxf((float)(start_s[b + 1] - start_s[b]), 1.0f);
    inv_g[threadIdx.x] = 1.0f / fmaxf((float)(start_g[b + 1] - start_g[b]), 1.0f);
  }
  __syncthreads();
  for (int i = threadIdx.x; i < 16 * 64; i += 256) {
    int ln = i >> 6, k = i & 63;
    zs[ln][k]      = psum[(size_t)(base + ln) * 64 + k] * inv_s[ln];
    zs[ln][64 + k] = psum[(size_t)(NBAT + base + ln) * 64 + k] * inv_g[ln];
  }
  if (threadIdx.x < 16) zs[threadIdx.x][128] = depth[base + threadIdx.x];
  __syncthreads();
  int g = threadIdx.x >> 4;
  int j = threadIdx.x & 15;
  int f0 = j * 4;
  float a0, a1, a2, a3;
  {
    const float4 b = *(const float4*)(b1 + f0);
    a0 = b.x; a1 = b.y; a2 = b.z; a3 = b.w;
  }
  for (int k = 0; k < 129; ++k) {
    float zv = zs[g][k];
    const float4 w = *(const float4*)(W1 + k * 64 + f0);
    a0 = fmaf(zv, w.x, a0); a1 = fmaf(zv, w.y, a1);
    a2 = fmaf(zv, w.z, a2); a3 = fmaf(zv, w.w, a3);
  }
  ys[f0 + 0][g] = relu_(a0);
  ys[f0 + 1][g] = relu_(a1);
  ys[f0 + 2][g] = relu_(a2);
  ys[f0 + 3][g] = relu_(a3);
  __syncthreads();
  float s = ys[f0 + 0][g] * W2[f0 + 0] + ys[f0 + 1][g] * W2[f0 + 1] +
            ys[f0 + 2][g] * W2[f0 + 2] + ys[f0 + 3][g] * W2[f0 + 3];
#pragma unroll
  for (int m = 1; m < 16; m <<= 1) s += __shfl_xor(s, m);
  if (j == 0) out[base + g] = s + b2[0];
}

}  // namespace

extern "C" void kernel_launch(void* const* d_in, const int* in_sizes, int n_in,
                              void* d_out, int out_size, void* d_ws, size_t ws_size,
                              hipStream_t stream) {
  const int*   names_s = (const int*)d_in[0];
  const int*   ei_s    = (const int*)d_in[1];
  const float* ea_s    = (const float*)d_in[2];
  const int*   bat_s   = (const int*)d_in[3];
  const int*   names_g = (const int*)d_in[4];
  const int*   ei_g    = (const int*)d_in[5];
  const float* ea_g    = (const float*)d_in[6];
  const int*   bat_g   = (const int*)d_in[7];
  const float* depth   = (const float*)d_in[8];
  const float* idW1 = (const float*)d_in[9],  *idb1 = (const float*)d_in[10];
  const float* idW2 = (const float*)d_in[11], *idb2 = (const float*)d_in[12];
  const float* edW1 = (const float*)d_in[13], *edb1 = (const float*)d_in[14];
  const float* edW2 = (const float*)d_in[15], *edb2 = (const float*)d_in[16];
  const float* s1W1 = (const float*)d_in[17], *s1b1 = (const float*)d_in[18];
  const float* s1W2 = (const float*)d_in[19], *s1b2 = (const float*)d_in[20];
  const float* s2W1 = (const float*)d_in[21], *s2b1 = (const float*)d_in[22];
  const float* s2W2 = (const float*)d_in[23], *s2b2 = (const float*)d_in[24];
  const float* s2LW = (const float*)d_in[25], *s2Lb = (const float*)d_in[26];
  const float* g1W1 = (const float*)d_in[27], *g1b1 = (const float*)d_in[28];
  const float* g1W2 = (const float*)d_in[29], *g1b2 = (const float*)d_in[30];
  const float* g2W1 = (const float*)d_in[31], *g2b1 = (const float*)d_in[32];
  const float* g2W2 = (const float*)d_in[33], *g2b2 = (const float*)d_in[34];
  const float* g2LW = (const float*)d_in[35], *g2Lb = (const float*)d_in[36];
  const float* rW1  = (const float*)d_in[37], *rb1  = (const float*)d_in[38];
  const float* rW2  = (const float*)d_in[39], *rb2  = (const float*)d_in[40];
  (void)in_sizes; (void)n_in; (void)out_size; (void)ws_size;

  char* ws = (char*)d_ws;
  size_t off = 0;
  auto alloc = [&](size_t bytes) -> char* {
    char* p = ws + off;
    off += (bytes + 255) & ~(size_t)255;
    return p;
  };
  float* tabs    = (float*)alloc((size_t)TAB_TOTAL * 4);
  // Activation region (76.8 MB): h2 [TN][64] at [0, 51.2M); h1 [TN][32]
  // at [51.2M, 76.8M). part scratch (NC*ENTCAP*8 = 32.03M) aliases the h2
  // region -- consumed by partition_to_csr before conv2 writes h2.
  char*  act   = alloc((size_t)TN * 64 * 4 + (size_t)TN * 32 * 4);  // 76.8 MB
  float* h2buf = (float*)act;
  float* h1buf = (float*)(act + (size_t)TN * 64 * 4);
  int2*  part  = (int2*)act;  // 32.03 MB <= 51.2 MB h2 region; dead before conv2
  __half* x0h  = (__half*)alloc((size_t)TN * 32 * 2);       // 12.8 MB fp16 shadow
  __half* x1h  = (__half*)alloc((size_t)TN * 64 * 2);       // 25.6 MB fp16 shadow
  int2*  colattr = (int2*) alloc((size_t)TE * 8);           // final CSR order
  int*   gcur    = (int*)  alloc((size_t)NC * 4);
  int*   rowptr  = (int*)  alloc((size_t)(TN + 1) * 4);
  int*   start_s = (int*)  alloc((size_t)(NBAT + 1) * 4);
  int*   start_g = (int*)  alloc((size_t)(NBAT + 1) * 4);
  float* psum    = (float*)alloc((size_t)2 * NBAT * 64 * 4);

  // build_tables also zeroes gcur + psum (memset dispatches folded in)
  build_tables<<<1, 256, 0, stream>>>(edW1, edb1, edW2, edb2, s2LW, s2Lb,
                                      g2LW, g2Lb, tabs, gcur, psum);

  // embed || partition || batch_bounds in one launch
  fused_front<<<ABLK + 782 + 782, 256, 0, stream>>>(
      names_s, names_g, idW1, idb1, idW2, idb2,
      ei_s, ei_s + NEDG, ea_s, ei_g, ei_g + NEDG, ea_g,
      bat_s, bat_g, tabs, x0h, gcur, part, start_s, start_g);
  partition_to_csr<<<NC, 256, 0, stream>>>(gcur, part, rowptr, colattr);

  conv1_dual<<<CONVBLK, 256, 0, stream>>>(x0h, rowptr, colattr, tabs, h1buf);
  mlp1_dual<<<TN / 64, 256, 0, stream>>>(h1buf,
                                         s1W1, s1b1, s1W2, s1b2,
                                         g1W1, g1b1, g1W2, g1b2, x1h);
  conv2_dual<<<CONVBLK, 256, 0, stream>>>(x1h, rowptr, colattr, tabs, h2buf);
  mlp2_pool_dual<<<TN / 64, 256, 0, stream>>>(h2buf,
                                              s2W1, s2b1, s2W2, s2b2,
                                              g2W1, g2b1, g2W2, g2b2,
                                              bat_s, bat_g, psum);
  regressor16<<<32, 256, 0, stream>>>(psum, start_s, start_g, depth,
                                      rW1, rb1, rW2, rb2, (float*)d_out);
}

// Round 11
// 555.412 us; speedup vs baseline: 1.0190x; 1.0190x over previous
//
#include <hip/hip_runtime.h>
#include <hip/hip_fp16.h>
#include <stdint.h>

namespace {

constexpr int NN   = 100000;    // nodes per graph
constexpr int TN   = 2 * NN;    // nodes across both graphs
constexpr int NEDG = 1600000;   // edges per graph
constexpr int TE   = 2 * NEDG;  // 3.2M edges across both graphs
constexpr int NBAT = 512;       // graphs per batch
constexpr int NSEG = 33;        // piecewise-linear segments of edge MLP (32 breakpoints)

// coarse partition: 256 dst-nodes per coarse bucket, fixed-capacity scratch
constexpr int NC     = 782;     // ceil(TN / 256)
constexpr int TILE   = 4096;    // edges per partition block (16 per thread)
constexpr int ABLK   = (TE + TILE - 1) / TILE;  // 782
constexpr int ENTCAP = 5120;    // bucket capacity (mean 4096, +16 sigma)

// persistent conv grids: 2048 blocks x 4 waves = 8192 waves (8 blocks/CU exact)
constexpr int CONVBLK = 2048;

// half2 LDS strides for the conv edge tables (16B-aligned for b128/b64 reads;
// stride*4 % 16 == 0, and stride mod 32 != 0 spreads the random seg id g
// across bank offsets)
constexpr int S1H = 20;  // conv1: 16 half2 (32 feat) + 4 pad
constexpr int S2H = 36;  // conv2: 32 half2 (64 feat) + 4 pad

// table layout (floats): bp[32] | d1[NSEG*32] | c1[NSEG*32] | per-enc {d2[NSEG*64], c2[NSEG*64]} x2
constexpr int TAB_BP = 0;
constexpr int TAB_D1 = 32;
constexpr int TAB_C1 = TAB_D1 + NSEG * 32;
constexpr int TAB_E2 = TAB_C1 + NSEG * 32;
constexpr int TAB_TOTAL = TAB_E2 + 4 * NSEG * 64;

__device__ __forceinline__ float relu_(float x) { return fmaxf(x, 0.0f); }

__device__ __forceinline__ float4 shfl_xor4(float4 v, int m) {
  return make_float4(__shfl_xor(v.x, m), __shfl_xor(v.y, m),
                     __shfl_xor(v.z, m), __shfl_xor(v.w, m));
}

__device__ __forceinline__ __half2 bch(int u) {
  return *reinterpret_cast<__half2*>(&u);
}
__device__ __forceinline__ int f2h2(float a, float b) {
  __half2 h = __floats2half2_rn(a, b);
  return *reinterpret_cast<int*>(&h);
}

// ---------------------------------------------------------------------------
// Precompute piecewise-linear tables for e(a) = relu(a*W1+b1)@W2+b2 and the
// folded e2(a) = e(a)@linW + linb. Exact reassociation of the reference math.
// Also zeroes gcur/psum (memset dispatches folded in; stream-ordered).
// ---------------------------------------------------------------------------
__global__ void build_tables(const float* __restrict__ eW1, const float* __restrict__ eb1,
                             const float* __restrict__ eW2, const float* __restrict__ eb2,
                             const float* __restrict__ sLW, const float* __restrict__ sLb,
                             const float* __restrict__ gLW, const float* __restrict__ gLb,
                             float* __restrict__ tabs,
                             int* __restrict__ gcur, float* __restrict__ psum) {
  __shared__ float traw[32];
  __shared__ float ts[32];
  __shared__ float dt[NSEG * 32];
  __shared__ float ct[NSEG * 32];
  int tid = threadIdx.x;
  // ---- folded memsets ----
  for (int i = tid; i < NC; i += blockDim.x) gcur[i] = 0;
  {
    float4* p4 = (float4*)psum;
    for (int i = tid; i < 2 * NBAT * 64 / 4; i += blockDim.x)
      p4[i] = make_float4(0.f, 0.f, 0.f, 0.f);
  }
  if (tid < 32) {
    float w = eW1[tid], b = eb1[tid];
    traw[tid] = (w != 0.0f) ? (-b / w) : 3.0e38f;
  }
  __syncthreads();
  if (tid < 32) {  // rank sort (stable for duplicates)
    float v = traw[tid];
    int r = 0;
    for (int j = 0; j < 32; ++j) {
      float u = traw[j];
      r += (u < v) || (u == v && j < tid);
    }
    ts[r] = v;
  }
  __syncthreads();
  if (tid < 32) tabs[TAB_BP + tid] = ts[tid];
  for (int idx = tid; idx < NSEG * 32; idx += blockDim.x) {
    int s = idx >> 5, j = idx & 31;
    float a;  // representative point strictly inside segment s: (ts[s-1], ts[s]]
    if (s == 0)            a = ts[0] - 1.0f;
    else if (s == NSEG - 1) a = ts[31] + 1.0f;
    else                   a = 0.5f * ts[s - 1] + 0.5f * ts[s];
    float d = 0.0f, c = 0.0f;
    for (int i = 0; i < 32; ++i) {
      float w = eW1[i], b = eb1[i];
      if (fmaf(a, w, b) > 0.0f) {
        float w2 = eW2[i * 32 + j];
        d = fmaf(w, w2, d);
        c = fmaf(b, w2, c);
      }
    }
    c += eb2[j];
    dt[idx] = d; ct[idx] = c;
    tabs[TAB_D1 + idx] = d;
    tabs[TAB_C1 + idx] = c;
  }
  __syncthreads();
  for (int idx = tid; idx < NSEG * 64; idx += blockDim.x) {
    int s = idx >> 6, k = idx & 63;
    float ds = 0.f, cs = 0.f, dg = 0.f, cg = 0.f;
    for (int j = 0; j < 32; ++j) {
      float dv = dt[s * 32 + j], cv = ct[s * 32 + j];
      float ws = sLW[j * 64 + k], wg = gLW[j * 64 + k];
      ds = fmaf(dv, ws, ds); cs = fmaf(cv, ws, cs);
      dg = fmaf(dv, wg, dg); cg = fmaf(cv, wg, cg);
    }
    cs += sLb[k]; cg += gLb[k];
    tabs[TAB_E2 + idx]                 = ds;
    tabs[TAB_E2 + NSEG * 64 + idx]     = cs;
    tabs[TAB_E2 + 2 * NSEG * 64 + idx] = dg;
    tabs[TAB_E2 + 3 * NSEG * 64 + idx] = cg;
  }
}

// ---------------------------------------------------------------------------
// Fused front: three INDEPENDENT jobs in one launch (block-range dispatch).
// R8 lesson: direct per-edge global scatter pays ~64B/edge write-allocate;
// the LDS staging here converts it into semi-contiguous bucket runs.
// ---------------------------------------------------------------------------
__global__ __launch_bounds__(256) void fused_front(
    const int* __restrict__ names_s, const int* __restrict__ names_g,
    const float* __restrict__ idW1, const float* __restrict__ idb1,
    const float* __restrict__ idW2, const float* __restrict__ idb2,
    const int* __restrict__ src_s, const int* __restrict__ dst_s, const float* __restrict__ attr_s,
    const int* __restrict__ src_g, const int* __restrict__ dst_g, const float* __restrict__ attr_g,
    const int* __restrict__ bat_s, const int* __restrict__ bat_g,
    const float* __restrict__ tabs,
    __half* __restrict__ x0h,
    int* __restrict__ gcur, int2* __restrict__ part,
    int* __restrict__ start_s, int* __restrict__ start_g) {
  __shared__ int hist[NC];
  __shared__ int lofs[NC];
  __shared__ int lcur[NC];
  __shared__ int2 sorted[TILE];
  __shared__ int addr[TILE];
  __shared__ int scanbuf[256];
  __shared__ float bp[32];
  int t = threadIdx.x;
  if (blockIdx.x < ABLK) {
    // ---- coarse partition tile ----
    if (t < 32) bp[t] = tabs[TAB_BP + t];
    for (int i = t; i < NC; i += 256) hist[i] = 0;
    __syncthreads();
    int base = blockIdx.x * TILE;
#pragma unroll
    for (int j = 0; j < 16; ++j) {
      int i = base + j * 256 + t;
      if (i < TE) {
        int d = (i < NEDG) ? dst_s[i] : (dst_g[i - NEDG] + NN);
        atomicAdd(&hist[d >> 8], 1);
      }
    }
    __syncthreads();
    int loc[4];
    int sum = 0;
#pragma unroll
    for (int j = 0; j < 4; ++j) {
      int b = t * 4 + j;
      int v = (b < NC) ? hist[b] : 0;
      loc[j] = sum; sum += v;
    }
    scanbuf[t] = sum;
    __syncthreads();
    for (int st = 1; st < 256; st <<= 1) {
      int u = (t >= st) ? scanbuf[t - st] : 0;
      __syncthreads();
      scanbuf[t] += u;
      __syncthreads();
    }
    int texcl = scanbuf[t] - sum;
#pragma unroll
    for (int j = 0; j < 4; ++j) {
      int b = t * 4 + j;
      if (b < NC) { lofs[b] = texcl + loc[j]; lcur[b] = 0; }
    }
    __syncthreads();
    // reserve space in each bucket's fixed-capacity region
    for (int b = t; b < NC; b += 256) {
      int c = hist[b];
      hist[b] = c ? atomicAdd(&gcur[b], c) : 0;
    }
    __syncthreads();
#pragma unroll
    for (int j = 0; j < 16; ++j) {
      int i = base + j * 256 + t;
      if (i < TE) {
        int sl, d; float a;
        if (i < NEDG) { sl = src_s[i]; d = dst_s[i]; a = attr_s[i]; }
        else { int k = i - NEDG; sl = src_g[k]; d = dst_g[k] + NN; a = attr_g[k]; }
        int seg = 0;
#pragma unroll
        for (int q = 0; q < 32; ++q) seg += (bp[q] < a);
        int c = d >> 8;
        int r = atomicAdd(&lcur[c], 1);
        int s = lofs[c] + r;
        sorted[s] = make_int2(sl | ((d & 255) << 17) | (seg << 25), __float_as_int(a));
        addr[s] = c * ENTCAP + hist[c] + r;
      }
    }
    __syncthreads();
    int tot = (base + TILE <= TE) ? TILE : (TE - base);
    for (int s = t; s < tot; s += 256) part[addr[s]] = sorted[s];
  } else if (blockIdx.x < ABLK + 782) {
    // ---- node embed (both graphs, fp16 shadow only; self term read as fp16) ----
    int n = (blockIdx.x - ABLK) * 256 + t;
    if (n >= TN) return;
    int name = (n < NN) ? names_s[n] : names_g[n - NN];
    float norm = ((float)name + 2.0f) / 281474976710655.0f;
    norm = fminf(fmaxf(norm, 0.0f), 1.0f);
    float h[32];
#pragma unroll
    for (int i = 0; i < 32; ++i) h[i] = relu_(fmaf(norm, idW1[i], idb1[i]));
    int2* outh = (int2*)(x0h + (size_t)n * 32);
    for (int j0 = 0; j0 < 32; j0 += 4) {
      float a0 = idb2[j0], a1 = idb2[j0 + 1], a2 = idb2[j0 + 2], a3 = idb2[j0 + 3];
#pragma unroll
      for (int i = 0; i < 32; ++i) {
        float hv = h[i];
        a0 = fmaf(hv, idW2[i * 32 + j0],     a0);
        a1 = fmaf(hv, idW2[i * 32 + j0 + 1], a1);
        a2 = fmaf(hv, idW2[i * 32 + j0 + 2], a2);
        a3 = fmaf(hv, idW2[i * 32 + j0 + 3], a3);
      }
      outh[j0 >> 2] = make_int2(f2h2(a0, a1), f2h2(a2, a3));
    }
  } else {
    // ---- batch boundaries ----
    int blk = blockIdx.x - ABLK - 782;
    int half = blk >= 391;
    const int* bat = half ? bat_g : bat_s;
    int* start = half ? start_g : start_s;
    int i = (blk - half * 391) * 256 + t;
    if (i >= NN) return;
    int cur = bat[i];
    int prev = (i == 0) ? -1 : bat[i - 1];
    for (int b = prev + 1; b <= cur; ++b) start[b] = i;
    if (i == NN - 1) {
      for (int b = cur + 1; b <= NBAT; ++b) start[b] = NN;
    }
  }
}

// ---------------------------------------------------------------------------
// partition -> CSR with the coarse scan INLINED (one fewer launch).
// ---------------------------------------------------------------------------
__global__ __launch_bounds__(256) void partition_to_csr(
    const int* __restrict__ gcur,
    const int2* __restrict__ part,
    int* __restrict__ rowptr, int2* __restrict__ colattr) {
  __shared__ int2 outE[ENTCAP];  // 40 KB
  __shared__ int hist[256];
  __shared__ int cur[256];
  __shared__ int sc[256];
  int t = threadIdx.x, b = blockIdx.x;  // grid exact: NC
  // ---- inline exclusive scan: obase = sum_{i<b} min(gcur[i], ENTCAP) ----
  {
    int acc = 0;
    for (int i = t; i < b; i += 256) acc += min(gcur[i], ENTCAP);
    sc[t] = acc;
    __syncthreads();
    for (int st = 128; st > 0; st >>= 1) {
      if (t < st) sc[t] += sc[t + st];
      __syncthreads();
    }
  }
  int obase = sc[0];
  if (b == 0 && t == 0) rowptr[TN] = TE;
  __syncthreads();  // done reading sc; reuse below
  hist[t] = 0;
  __syncthreads();
  int cnt = min(gcur[b], ENTCAP);
  int ibase = b * ENTCAP;
  for (int i = t; i < cnt; i += 256)
    atomicAdd(&hist[(part[ibase + i].x >> 17) & 255], 1);
  __syncthreads();
  int v = hist[t];
  sc[t] = v;
  __syncthreads();
  for (int st = 1; st < 256; st <<= 1) {
    int u = (t >= st) ? sc[t - st] : 0;
    __syncthreads();
    sc[t] += u;
    __syncthreads();
  }
  int excl = sc[t] - v;
  int gnode = b * 256 + t;
  if (gnode < TN) rowptr[gnode] = obase + excl;
  cur[t] = excl;
  __syncthreads();
  for (int i = t; i < cnt; i += 256) {
    int2 e = part[ibase + i];
    int dl = (e.x >> 17) & 255;
    int srcn = e.x & 0x1FFFF;
    int seg = (e.x >> 25) & 63;
    int pos = atomicAdd(&cur[dl], 1);
    float af = __int_as_float(e.y);
    // conv format: src<2^17 | seg<<20; attr pre-packed as half2(a,a)
    // (bit-identical to the conv-side __floats2half2_rn it replaces)
    outE[pos] = make_int2(srcn | (seg << 20), f2h2(af, af));
  }
  __syncthreads();
  for (int i = t; i < cnt; i += 256) colattr[obase + i] = outE[i];
}

// ---------------------------------------------------------------------------
// conv1: R2/R9 proven body (NO peel/pipeline -- R10 showed the peel's fixed
// overhead flips negative on conv1's half-size per-node work: total +8us).
// Persistent blocks; next-node rowptr prefetched at loop top, consumed next
// iteration (fully hidden).
// ---------------------------------------------------------------------------
__global__ __launch_bounds__(256) void conv1_dual(
    const __half* __restrict__ x0h,
    const int* __restrict__ rowptr, const int2* __restrict__ colattr,
    const float* __restrict__ tabs, float* __restrict__ hb) {
  __shared__ __half2 dt2[NSEG * S1H];
  __shared__ __half2 ct2[NSEG * S1H];
  for (int i = threadIdx.x; i < NSEG * 16; i += 256) {
    int s = i >> 4, j = i & 15;
    dt2[s * S1H + j] = __floats2half2_rn(tabs[TAB_D1 + s * 32 + 2 * j],
                                         tabs[TAB_D1 + s * 32 + 2 * j + 1]);
    ct2[s * S1H + j] = __floats2half2_rn(tabs[TAB_C1 + s * 32 + 2 * j],
                                         tabs[TAB_C1 + s * 32 + 2 * j + 1]);
  }
  __syncthreads();
  int lane = threadIdx.x & 63;
  int sub = lane & 7;        // 8 edges in flight (x2 unroll = 16)
  int f0  = (lane >> 3) * 4; // 4 features per lane
  int h0  = (lane >> 3) * 2; // half2 index
  int wid = blockIdx.x * 4 + (threadIdx.x >> 6);  // [0, 8192)
  int nb = rowptr[wid], ne = rowptr[wid + 1];     // prefetched pair
  for (int n = wid; n < TN; n += 4 * CONVBLK) {
    int beg = nb, end = ne;
    int n2 = n + 4 * CONVBLK;
    if (n2 < TN) { nb = rowptr[n2]; ne = rowptr[n2 + 1]; }  // prefetch next node
    const __half* xb = x0h + (n >= NN ? (size_t)NN * 32 : 0);  // src ids graph-local
    int2 sv = make_int2(0, 0);
    if (sub == 0) sv = *(const int2*)(x0h + (size_t)n * 32 + f0);
    float4 acc = make_float4(0.f, 0.f, 0.f, 0.f);
    for (int k = beg + sub; k < end; k += 16) {
      int2 ca0 = colattr[k];
      int kb = k + 8;
      bool has1 = kb < end;
      int2 ca1 = has1 ? colattr[kb] : ca0;
      unsigned p0 = (unsigned)ca0.x, p1 = (unsigned)ca1.x;
      int s0 = (int)(p0 & 0xFFFFFu), g0 = (int)(p0 >> 20);
      int s1 = (int)(p1 & 0xFFFFFu), g1 = (int)(p1 >> 20);
      __half2 az0 = bch(ca0.y);
      __half2 az1 = bch(ca1.y);
      int2 xv0 = *(const int2*)(xb + (size_t)s0 * 32 + f0);
      int2 xv1 = *(const int2*)(xb + (size_t)s1 * 32 + f0);
      int2 dv0 = *(const int2*)&dt2[g0 * S1H + h0];
      int2 cv0 = *(const int2*)&ct2[g0 * S1H + h0];
      __half2 v;
      float2 f;
      v = __hadd2(bch(xv0.x), __hfma2(az0, bch(dv0.x), bch(cv0.x)));
      f = __half22float2(v); acc.x += relu_(f.x); acc.y += relu_(f.y);
      v = __hadd2(bch(xv0.y), __hfma2(az0, bch(dv0.y), bch(cv0.y)));
      f = __half22float2(v); acc.z += relu_(f.x); acc.w += relu_(f.y);
      if (has1) {
        int2 dv1 = *(const int2*)&dt2[g1 * S1H + h0];
        int2 cv1 = *(const int2*)&ct2[g1 * S1H + h0];
        v = __hadd2(bch(xv1.x), __hfma2(az1, bch(dv1.x), bch(cv1.x)));
        f = __half22float2(v); acc.x += relu_(f.x); acc.y += relu_(f.y);
        v = __hadd2(bch(xv1.y), __hfma2(az1, bch(dv1.y), bch(cv1.y)));
        f = __half22float2(v); acc.z += relu_(f.x); acc.w += relu_(f.y);
      }
    }
#pragma unroll
    for (int m = 1; m < 8; m <<= 1) {
      float4 o = shfl_xor4(acc, m);
      acc.x += o.x; acc.y += o.y; acc.z += o.z; acc.w += o.w;
    }
    if (sub == 0) {
      float2 t0 = __half22float2(bch(sv.x)), t1 = __half22float2(bch(sv.y));
      *(float4*)(hb + (size_t)n * 32 + f0) =
          make_float4(t0.x + acc.x, t0.y + acc.y, t1.x + acc.z, t1.y + acc.w);
    }
  }
}

// ---------------------------------------------------------------------------
// conv2: DEPTH-2 software pipeline (R10, proven 98.0 vs 100.6us): rowptr two
// nodes ahead, first-iteration colattr one node ahead (address from begN
// produced last body). Peeled masked first iteration covers deg<=16; tail is
// the proven R2 body. Worth it here (per-node body 2x conv1's) -- the same
// peel regressed conv1.
// ---------------------------------------------------------------------------
__device__ __forceinline__ void e2mm(int4 xv, unsigned p, int h0, __half2 az, float m,
                                     const __half2* dt2, const __half2* ct2,
                                     float4& A, float4& B) {
  int g = (int)(p >> 20);
  int4 dv = *(const int4*)&dt2[g * S2H + h0];
  int4 cv = *(const int4*)&ct2[g * S2H + h0];
  __half2 v; float2 f;
  v = __hadd2(bch(xv.x), __hfma2(az, bch(dv.x), bch(cv.x)));
  f = __half22float2(v); A.x = fmaf(m, relu_(f.x), A.x); A.y = fmaf(m, relu_(f.y), A.y);
  v = __hadd2(bch(xv.y), __hfma2(az, bch(dv.y), bch(cv.y)));
  f = __half22float2(v); A.z = fmaf(m, relu_(f.x), A.z); A.w = fmaf(m, relu_(f.y), A.w);
  v = __hadd2(bch(xv.z), __hfma2(az, bch(dv.z), bch(cv.z)));
  f = __half22float2(v); B.x = fmaf(m, relu_(f.x), B.x); B.y = fmaf(m, relu_(f.y), B.y);
  v = __hadd2(bch(xv.w), __hfma2(az, bch(dv.w), bch(cv.w)));
  f = __half22float2(v); B.z = fmaf(m, relu_(f.x), B.z); B.w = fmaf(m, relu_(f.y), B.w);
}

__global__ __launch_bounds__(256) void conv2_dual(
    const __half* __restrict__ x1h,
    const int* __restrict__ rowptr, const int2* __restrict__ colattr,
    const float* __restrict__ tabs, float* __restrict__ hb) {
  __shared__ __half2 dt2[NSEG * S2H];
  __shared__ __half2 ct2[NSEG * S2H];
  int halfg = blockIdx.x >= (CONVBLK / 2);  // blocks [0,1024): graph s; [1024,2048): graph g
  const float* d2 = tabs + TAB_E2 + (size_t)halfg * 2 * NSEG * 64;
  for (int i = threadIdx.x; i < NSEG * 32; i += 256) {
    int s = i >> 5, j = i & 31;
    dt2[s * S2H + j] = __floats2half2_rn(d2[s * 64 + 2 * j], d2[s * 64 + 2 * j + 1]);
    ct2[s * S2H + j] = __floats2half2_rn(d2[NSEG * 64 + s * 64 + 2 * j],
                                         d2[NSEG * 64 + s * 64 + 2 * j + 1]);
  }
  __syncthreads();
  const __half* xb = x1h + (size_t)halfg * NN * 64;  // src ids graph-local
  int lane = threadIdx.x & 63;
  int sub = lane & 7;        // 8 edges in flight (x2 unroll = 16)
  int f0  = (lane >> 3) * 8; // 8 features per lane
  int h0  = (lane >> 3) * 4; // half2 index
  constexpr int STR2 = 2 * CONVBLK;  // 4096 waves per half
  int wid = (blockIdx.x - halfg * (CONVBLK / 2)) * 4 + (threadIdx.x >> 6);
  int nlim = halfg * NN + NN;
  int n = halfg * NN + wid;
  // pipeline prologue
  int begC = rowptr[n], endC = rowptr[n + 1];
  int begN = 0, endN = 0;
  if (n + STR2 < nlim) { begN = rowptr[n + STR2]; endN = rowptr[n + STR2 + 1]; }
  int2 c0 = colattr[min(begC + sub, TE - 1)];
  int2 c1 = colattr[min(begC + sub + 8, TE - 1)];
  for (; n < nlim; n += STR2) {
    int begNN = 0, endNN = 0;
    int n2 = n + 2 * STR2;
    if (n2 < nlim) { begNN = rowptr[n2]; endNN = rowptr[n2 + 1]; }
    int2 cN0 = colattr[min(begN + sub, TE - 1)];
    int2 cN1 = colattr[min(begN + sub + 8, TE - 1)];
    int4 sv0 = make_int4(0, 0, 0, 0);
    if (sub == 0) sv0 = *(const int4*)(x1h + (size_t)n * 64 + f0);
    float4 accA = make_float4(0.f, 0.f, 0.f, 0.f);
    float4 accB = make_float4(0.f, 0.f, 0.f, 0.f);
    // peeled first iteration (deg <= 16 common case)
    {
      int k0 = begC + sub;
      bool v0 = k0 < endC, v1 = k0 + 8 < endC;
      unsigned p0 = (unsigned)c0.x, p1 = (unsigned)c1.x;
      int4 xv0 = make_int4(0, 0, 0, 0), xv1 = make_int4(0, 0, 0, 0);
      if (v0) xv0 = *(const int4*)(xb + (size_t)(p0 & 0xFFFFFu) * 64 + f0);
      if (v1) xv1 = *(const int4*)(xb + (size_t)(p1 & 0xFFFFFu) * 64 + f0);
      e2mm(xv0, p0, h0, bch(c0.y), v0 ? 1.f : 0.f, dt2, ct2, accA, accB);
      e2mm(xv1, p1, h0, bch(c1.y), v1 ? 1.f : 0.f, dt2, ct2, accA, accB);
    }
    // tail (deg > 16): proven R2 body
    for (int k = begC + 16 + sub; k < endC; k += 16) {
      int2 ca0 = colattr[k];
      int kb = k + 8;
      bool has1 = kb < endC;
      int2 ca1 = has1 ? colattr[kb] : ca0;
      unsigned p0 = (unsigned)ca0.x, p1 = (unsigned)ca1.x;
      int s0 = (int)(p0 & 0xFFFFFu), g0 = (int)(p0 >> 20);
      int s1 = (int)(p1 & 0xFFFFFu), g1 = (int)(p1 >> 20);
      __half2 az0 = bch(ca0.y);
      __half2 az1 = bch(ca1.y);
      int4 xv0 = *(const int4*)(xb + (size_t)s0 * 64 + f0);
      int4 xv1 = *(const int4*)(xb + (size_t)s1 * 64 + f0);
      int4 dv0 = *(const int4*)&dt2[g0 * S2H + h0];
      int4 cv0 = *(const int4*)&ct2[g0 * S2H + h0];
      __half2 v;
      float2 f;
      v = __hadd2(bch(xv0.x), __hfma2(az0, bch(dv0.x), bch(cv0.x)));
      f = __half22float2(v); accA.x += relu_(f.x); accA.y += relu_(f.y);
      v = __hadd2(bch(xv0.y), __hfma2(az0, bch(dv0.y), bch(cv0.y)));
      f = __half22float2(v); accA.z += relu_(f.x); accA.w += relu_(f.y);
      v = __hadd2(bch(xv0.z), __hfma2(az0, bch(dv0.z), bch(cv0.z)));
      f = __half22float2(v); accB.x += relu_(f.x); accB.y += relu_(f.y);
      v = __hadd2(bch(xv0.w), __hfma2(az0, bch(dv0.w), bch(cv0.w)));
      f = __half22float2(v); accB.z += relu_(f.x); accB.w += relu_(f.y);
      if (has1) {
        int4 dv1 = *(const int4*)&dt2[g1 * S2H + h0];
        int4 cv1 = *(const int4*)&ct2[g1 * S2H + h0];
        v = __hadd2(bch(xv1.x), __hfma2(az1, bch(dv1.x), bch(cv1.x)));
        f = __half22float2(v); accA.x += relu_(f.x); accA.y += relu_(f.y);
        v = __hadd2(bch(xv1.y), __hfma2(az1, bch(dv1.y), bch(cv1.y)));
        f = __half22float2(v); accA.z += relu_(f.x); accA.w += relu_(f.y);
        v = __hadd2(bch(xv1.z), __hfma2(az1, bch(dv1.z), bch(cv1.z)));
        f = __half22float2(v); accB.x += relu_(f.x); accB.y += relu_(f.y);
        v = __hadd2(bch(xv1.w), __hfma2(az1, bch(dv1.w), bch(cv1.w)));
        f = __half22float2(v); accB.z += relu_(f.x); accB.w += relu_(f.y);
      }
    }
#pragma unroll
    for (int m = 1; m < 8; m <<= 1) {
      float4 oA = shfl_xor4(accA, m);
      float4 oB = shfl_xor4(accB, m);
      accA.x += oA.x; accA.y += oA.y; accA.z += oA.z; accA.w += oA.w;
      accB.x += oB.x; accB.y += oB.y; accB.z += oB.z; accB.w += oB.w;
    }
    if (sub == 0) {
      float2 t0 = __half22float2(bch(sv0.x)), t1 = __half22float2(bch(sv0.y));
      float2 t2 = __half22float2(bch(sv0.z)), t3 = __half22float2(bch(sv0.w));
      float* op = hb + (size_t)n * 64 + f0;
      *(float4*)op       = make_float4(t0.x + accA.x, t0.y + accA.y, t1.x + accA.z, t1.y + accA.w);
      *(float4*)(op + 4) = make_float4(t2.x + accB.x, t2.y + accB.y, t3.x + accB.z, t3.y + accB.w);
    }
    // rotate pipeline
    begC = begN; endC = endN;
    begN = begNN; endN = endNN;
    c0 = cN0; c1 = cN1;
  }
}

// ---------------------------------------------------------------------------
// Per-node MLP2 (32 -> 64 -> 64) over BOTH graphs, fp16 shadow output ONLY.
// Register-tiled: thread owns 4 nodes x 4 features (16 independent chains).
// ---------------------------------------------------------------------------
__global__ __launch_bounds__(256) void mlp1_dual(
    const float* __restrict__ hin,
    const float* __restrict__ sW1, const float* __restrict__ sb1,
    const float* __restrict__ sW2, const float* __restrict__ sb2,
    const float* __restrict__ gW1, const float* __restrict__ gb1,
    const float* __restrict__ gW2, const float* __restrict__ gb2,
    __half* __restrict__ hout) {
  constexpr int IN = 32;
  __shared__ float hsT[IN][65];
  __shared__ float ysT[64][65];
  int base = blockIdx.x * 64;     // grid exact: TN/64 = 3125
  for (int idx = threadIdx.x; idx < 64 * IN; idx += 256) {
    int node = idx / IN, k = idx - node * IN;
    hsT[k][node] = hin[(size_t)(base + node) * IN + k];
  }
  __syncthreads();
  int nt = threadIdx.x >> 4, jx = threadIdx.x & 15;
  int n0 = nt * 4, f0 = jx * 4;
  bool isg = (base + n0) >= NN;
  const float* W1 = isg ? gW1 : sW1;
  const float* b1 = isg ? gb1 : sb1;
  const float* W2 = isg ? gW2 : sW2;
  const float* b2 = isg ? gb2 : sb2;
  float4 acc0, acc1, acc2, acc3;
  {
    const float4 b = *(const float4*)(b1 + f0);
    acc0 = b; acc1 = b; acc2 = b; acc3 = b;
  }
  for (int k = 0; k < IN; ++k) {
    const float4 h = *(const float4*)&hsT[k][n0];
    const float4 w = *(const float4*)(W1 + k * 64 + f0);
    acc0.x = fmaf(h.x, w.x, acc0.x); acc0.y = fmaf(h.x, w.y, acc0.y);
    acc0.z = fmaf(h.x, w.z, acc0.z); acc0.w = fmaf(h.x, w.w, acc0.w);
    acc1.x = fmaf(h.y, w.x, acc1.x); acc1.y = fmaf(h.y, w.y, acc1.y);
    acc1.z = fmaf(h.y, w.z, acc1.z); acc1.w = fmaf(h.y, w.w, acc1.w);
    acc2.x = fmaf(h.z, w.x, acc2.x); acc2.y = fmaf(h.z, w.y, acc2.y);
    acc2.z = fmaf(h.z, w.z, acc2.z); acc2.w = fmaf(h.z, w.w, acc2.w);
    acc3.x = fmaf(h.w, w.x, acc3.x); acc3.y = fmaf(h.w, w.y, acc3.y);
    acc3.z = fmaf(h.w, w.z, acc3.z); acc3.w = fmaf(h.w, w.w, acc3.w);
  }
  ysT[f0 + 0][n0 + 0] = relu_(acc0.x); ysT[f0 + 1][n0 + 0] = relu_(acc0.y);
  ysT[f0 + 2][n0 + 0] = relu_(acc0.z); ysT[f0 + 3][n0 + 0] = relu_(acc0.w);
  ysT[f0 + 0][n0 + 1] = relu_(acc1.x); ysT[f0 + 1][n0 + 1] = relu_(acc1.y);
  ysT[f0 + 2][n0 + 1] = relu_(acc1.z); ysT[f0 + 3][n0 + 1] = relu_(acc1.w);
  ysT[f0 + 0][n0 + 2] = relu_(acc2.x); ysT[f0 + 1][n0 + 2] = relu_(acc2.y);
  ysT[f0 + 2][n0 + 2] = relu_(acc2.z); ysT[f0 + 3][n0 + 2] = relu_(acc2.w);
  ysT[f0 + 0][n0 + 3] = relu_(acc3.x); ysT[f0 + 1][n0 + 3] = relu_(acc3.y);
  ysT[f0 + 2][n0 + 3] = relu_(acc3.z); ysT[f0 + 3][n0 + 3] = relu_(acc3.w);
  __syncthreads();
  {
    const float4 b = *(const float4*)(b2 + f0);
    acc0 = b; acc1 = b; acc2 = b; acc3 = b;
  }
  for (int k = 0; k < 64; ++k) {
    const float4 h = *(const float4*)&ysT[k][n0];
    const float4 w = *(const float4*)(W2 + k * 64 + f0);
    acc0.x = fmaf(h.x, w.x, acc0.x); acc0.y = fmaf(h.x, w.y, acc0.y);
    acc0.z = fmaf(h.x, w.z, acc0.z); acc0.w = fmaf(h.x, w.w, acc0.w);
    acc1.x = fmaf(h.y, w.x, acc1.x); acc1.y = fmaf(h.y, w.y, acc1.y);
    acc1.z = fmaf(h.y, w.z, acc1.z); acc1.w = fmaf(h.y, w.w, acc1.w);
    acc2.x = fmaf(h.z, w.x, acc2.x); acc2.y = fmaf(h.z, w.y, acc2.y);
    acc2.z = fmaf(h.z, w.z, acc2.z); acc2.w = fmaf(h.z, w.w, acc2.w);
    acc3.x = fmaf(h.w, w.x, acc3.x); acc3.y = fmaf(h.w, w.y, acc3.y);
    acc3.z = fmaf(h.w, w.z, acc3.z); acc3.w = fmaf(h.w, w.w, acc3.w);
  }
  float4 o;
  o = make_float4(relu_(acc0.x), relu_(acc0.y), relu_(acc0.z), relu_(acc0.w));
  *(int2*)(hout + (size_t)(base + n0 + 0) * 64 + f0) = make_int2(f2h2(o.x, o.y), f2h2(o.z, o.w));
  o = make_float4(relu_(acc1.x), relu_(acc1.y), relu_(acc1.z), relu_(acc1.w));
  *(int2*)(hout + (size_t)(base + n0 + 1) * 64 + f0) = make_int2(f2h2(o.x, o.y), f2h2(o.z, o.w));
  o = make_float4(relu_(acc2.x), relu_(acc2.y), relu_(acc2.z), relu_(acc2.w));
  *(int2*)(hout + (size_t)(base + n0 + 2) * 64 + f0) = make_int2(f2h2(o.x, o.y), f2h2(o.z, o.w));
  o = make_float4(relu_(acc3.x), relu_(acc3.y), relu_(acc3.z), relu_(acc3.w));
  *(int2*)(hout + (size_t)(base + n0 + 3) * 64 + f0) = make_int2(f2h2(o.x, o.y), f2h2(o.z, o.w));
}

// ---------------------------------------------------------------------------
// mlp2 + pool fused: outputs go to LDS, per-block run-length reduction over
// batch segments, ~300 fp32 atomics/block into psum (no x2 round-trip).
// ---------------------------------------------------------------------------
__global__ __launch_bounds__(256) void mlp2_pool_dual(
    const float* __restrict__ hin,
    const float* __restrict__ sW1, const float* __restrict__ sb1,
    const float* __restrict__ sW2, const float* __restrict__ sb2,
    const float* __restrict__ gW1, const float* __restrict__ gb1,
    const float* __restrict__ gW2, const float* __restrict__ gb2,
    const int* __restrict__ bat_s, const int* __restrict__ bat_g,
    float* __restrict__ psum) {
  constexpr int IN = 64;
  __shared__ float hsT[IN][65];
  __shared__ float ysT[64][65];
  __shared__ int pid[64];
  int base = blockIdx.x * 64;     // grid exact: TN/64 = 3125
  for (int idx = threadIdx.x; idx < 64 * IN; idx += 256) {
    int node = idx / IN, k = idx - node * IN;
    hsT[k][node] = hin[(size_t)(base + node) * IN + k];
  }
  if (threadIdx.x < 64) {
    int gb = base + threadIdx.x;
    pid[threadIdx.x] = (gb < NN) ? bat_s[gb] : (NBAT + bat_g[gb - NN]);
  }
  __syncthreads();
  int nt = threadIdx.x >> 4, jx = threadIdx.x & 15;
  int n0 = nt * 4, f0 = jx * 4;
  bool isg = (base + n0) >= NN;
  const float* W1 = isg ? gW1 : sW1;
  const float* b1 = isg ? gb1 : sb1;
  const float* W2 = isg ? gW2 : sW2;
  const float* b2 = isg ? gb2 : sb2;
  float4 acc0, acc1, acc2, acc3;
  {
    const float4 b = *(const float4*)(b1 + f0);
    acc0 = b; acc1 = b; acc2 = b; acc3 = b;
  }
  for (int k = 0; k < IN; ++k) {
    const float4 h = *(const float4*)&hsT[k][n0];
    const float4 w = *(const float4*)(W1 + k * 64 + f0);
    acc0.x = fmaf(h.x, w.x, acc0.x); acc0.y = fmaf(h.x, w.y, acc0.y);
    acc0.z = fmaf(h.x, w.z, acc0.z); acc0.w = fmaf(h.x, w.w, acc0.w);
    acc1.x = fmaf(h.y, w.x, acc1.x); acc1.y = fmaf(h.y, w.y, acc1.y);
    acc1.z = fmaf(h.y, w.z, acc1.z); acc1.w = fmaf(h.y, w.w, acc1.w);
    acc2.x = fmaf(h.z, w.x, acc2.x); acc2.y = fmaf(h.z, w.y, acc2.y);
    acc2.z = fmaf(h.z, w.z, acc2.z); acc2.w = fmaf(h.z, w.w, acc2.w);
    acc3.x = fmaf(h.w, w.x, acc3.x); acc3.y = fmaf(h.w, w.y, acc3.y);
    acc3.z = fmaf(h.w, w.z, acc3.z); acc3.w = fmaf(h.w, w.w, acc3.w);
  }
  ysT[f0 + 0][n0 + 0] = relu_(acc0.x); ysT[f0 + 1][n0 + 0] = relu_(acc0.y);
  ysT[f0 + 2][n0 + 0] = relu_(acc0.z); ysT[f0 + 3][n0 + 0] = relu_(acc0.w);
  ysT[f0 + 0][n0 + 1] = relu_(acc1.x); ysT[f0 + 1][n0 + 1] = relu_(acc1.y);
  ysT[f0 + 2][n0 + 1] = relu_(acc1.z); ysT[f0 + 3][n0 + 1] = relu_(acc1.w);
  ysT[f0 + 0][n0 + 2] = relu_(acc2.x); ysT[f0 + 1][n0 + 2] = relu_(acc2.y);
  ysT[f0 + 2][n0 + 2] = relu_(acc2.z); ysT[f0 + 3][n0 + 2] = relu_(acc2.w);
  ysT[f0 + 0][n0 + 3] = relu_(acc3.x); ysT[f0 + 1][n0 + 3] = relu_(acc3.y);
  ysT[f0 + 2][n0 + 3] = relu_(acc3.z); ysT[f0 + 3][n0 + 3] = relu_(acc3.w);
  __syncthreads();
  {
    const float4 b = *(const float4*)(b2 + f0);
    acc0 = b; acc1 = b; acc2 = b; acc3 = b;
  }
  for (int k = 0; k < 64; ++k) {
    const float4 h = *(const float4*)&ysT[k][n0];
    const float4 w = *(const float4*)(W2 + k * 64 + f0);
    acc0.x = fmaf(h.x, w.x, acc0.x); acc0.y = fmaf(h.x, w.y, acc0.y);
    acc0.z = fmaf(h.x, w.z, acc0.z); acc0.w = fmaf(h.x, w.w, acc0.w);
    acc1.x = fmaf(h.y, w.x, acc1.x); acc1.y = fmaf(h.y, w.y, acc1.y);
    acc1.z = fmaf(h.y, w.z, acc1.z); acc1.w = fmaf(h.y, w.w, acc1.w);
    acc2.x = fmaf(h.z, w.x, acc2.x); acc2.y = fmaf(h.z, w.y, acc2.y);
    acc2.z = fmaf(h.z, w.z, acc2.z); acc2.w = fmaf(h.z, w.w, acc2.w);
    acc3.x = fmaf(h.w, w.x, acc3.x); acc3.y = fmaf(h.w, w.y, acc3.y);
    acc3.z = fmaf(h.w, w.z, acc3.z); acc3.w = fmaf(h.w, w.w, acc3.w);
  }
  __syncthreads();  // all reads of ysT done; reuse it for outputs [f][node]
  ysT[f0 + 0][n0 + 0] = relu_(acc0.x); ysT[f0 + 1][n0 + 0] = relu_(acc0.y);
  ysT[f0 + 2][n0 + 0] = relu_(acc0.z); ysT[f0 + 3][n0 + 0] = relu_(acc0.w);
  ysT[f0 + 0][n0 + 1] = relu_(acc1.x); ysT[f0 + 1][n0 + 1] = relu_(acc1.y);
  ysT[f0 + 2][n0 + 1] = relu_(acc1.z); ysT[f0 + 3][n0 + 1] = relu_(acc1.w);
  ysT[f0 + 0][n0 + 2] = relu_(acc2.x); ysT[f0 + 1][n0 + 2] = relu_(acc2.y);
  ysT[f0 + 2][n0 + 2] = relu_(acc2.z); ysT[f0 + 3][n0 + 2] = relu_(acc2.w);
  ysT[f0 + 0][n0 + 3] = relu_(acc3.x); ysT[f0 + 1][n0 + 3] = relu_(acc3.y);
  ysT[f0 + 2][n0 + 3] = relu_(acc3.z); ysT[f0 + 3][n0 + 3] = relu_(acc3.w);
  __syncthreads();
  // pool: thread (c, f) sums nodes [c*16, c*16+16) of feature f, flushing
  // per batch-segment run (nodes are sorted by batch within each graph)
  int c = threadIdx.x >> 6, f = threadIdx.x & 63;
  int cur = pid[c * 16];
  float run = 0.0f;
  for (int i = 0; i < 16; ++i) {
    int nx = c * 16 + i;
    int p = pid[nx];
    if (p != cur) { atomicAdd(&psum[(size_t)cur * 64 + f], run); run = 0.0f; cur = p; }
    run += ysT[f][nx];
  }
  atomicAdd(&psum[(size_t)cur * 64 + f], run);
}

// ---------------------------------------------------------------------------
// regressor: out[b] = relu([s_mean|g_mean|depth] @ rW1 + rb1) @ rW2 + rb2
// ---------------------------------------------------------------------------
__global__ __launch_bounds__(256) void regressor16(
    const float* __restrict__ psum,
    const int* __restrict__ start_s, const int* __restrict__ start_g,
    const float* __restrict__ depth,
    const float* __restrict__ W1, const float* __restrict__ b1,
    const float* __restrict__ W2, const float* __restrict__ b2,
    float* __restrict__ out) {
  __shared__ float zs[16][132];   // [row][k], k in [0,129)
  __shared__ float ys[64][17];
  __shared__ float inv_s[16], inv_g[16];
  int base = blockIdx.x * 16;     // grid 32 blocks x 16 rows = 512 exact
  if (threadIdx.x < 16) {
    int b = base + threadIdx.x;
    inv_s[threadIdx.x] = 1.0f / fmaxf((float)(start_s[b + 1] - start_s[b]), 1.0f);
    inv_g[threadIdx.x] = 1.0f / fmaxf((float)(start_g[b + 1] - start_g[b]), 1.0f);
  }
  __syncthreads();
  for (int i = threadIdx.x; i < 16 * 64; i += 256) {
    int ln = i >> 6, k = i & 63;
    zs[ln][k]      = psum[(size_t)(base + ln) * 64 + k] * inv_s[ln];
    zs[ln][64 + k] = psum[(size_t)(NBAT + base + ln) * 64 + k] * inv_g[ln];
  }
  if (threadIdx.x < 16) zs[threadIdx.x][128] = depth[base + threadIdx.x];
  __syncthreads();
  int g = threadIdx.x >> 4;
  int j = threadIdx.x & 15;
  int f0 = j * 4;
  float a0, a1, a2, a3;
  {
    const float4 b = *(const float4*)(b1 + f0);
    a0 = b.x; a1 = b.y; a2 = b.z; a3 = b.w;
  }
  for (int k = 0; k < 129; ++k) {
    float zv = zs[g][k];
    const float4 w = *(const float4*)(W1 + k * 64 + f0);
    a0 = fmaf(zv, w.x, a0); a1 = fmaf(zv, w.y, a1);
    a2 = fmaf(zv, w.z, a2); a3 = fmaf(zv, w.w, a3);
  }
  ys[f0 + 0][g] = relu_(a0);
  ys[f0 + 1][g] = relu_(a1);
  ys[f0 + 2][g] = relu_(a2);
  ys[f0 + 3][g] = relu_(a3);
  __syncthreads();
  float s = ys[f0 + 0][g] * W2[f0 + 0] + ys[f0 + 1][g] * W2[f0 + 1] +
            ys[f0 + 2][g] * W2[f0 + 2] + ys[f0 + 3][g] * W2[f0 + 3];
#pragma unroll
  for (int m = 1; m < 16; m <<= 1) s += __shfl_xor(s, m);
  if (j == 0) out[base + g] = s + b2[0];
}

}  // namespace

extern "C" void kernel_launch(void* const* d_in, const int* in_sizes, int n_in,
                              void* d_out, int out_size, void* d_ws, size_t ws_size,
                              hipStream_t stream) {
  const int*   names_s = (const int*)d_in[0];
  const int*   ei_s    = (const int*)d_in[1];
  const float* ea_s    = (const float*)d_in[2];
  const int*   bat_s   = (const int*)d_in[3];
  const int*   names_g = (const int*)d_in[4];
  const int*   ei_g    = (const int*)d_in[5];
  const float* ea_g    = (const float*)d_in[6];
  const int*   bat_g   = (const int*)d_in[7];
  const float* depth   = (const float*)d_in[8];
  const float* idW1 = (const float*)d_in[9],  *idb1 = (const float*)d_in[10];
  const float* idW2 = (const float*)d_in[11], *idb2 = (const float*)d_in[12];
  const float* edW1 = (const float*)d_in[13], *edb1 = (const float*)d_in[14];
  const float* edW2 = (const float*)d_in[15], *edb2 = (const float*)d_in[16];
  const float* s1W1 = (const float*)d_in[17], *s1b1 = (const float*)d_in[18];
  const float* s1W2 = (const float*)d_in[19], *s1b2 = (const float*)d_in[20];
  const float* s2W1 = (const float*)d_in[21], *s2b1 = (const float*)d_in[22];
  const float* s2W2 = (const float*)d_in[23], *s2b2 = (const float*)d_in[24];
  const float* s2LW = (const float*)d_in[25], *s2Lb = (const float*)d_in[26];
  const float* g1W1 = (const float*)d_in[27], *g1b1 = (const float*)d_in[28];
  const float* g1W2 = (const float*)d_in[29], *g1b2 = (const float*)d_in[30];
  const float* g2W1 = (const float*)d_in[31], *g2b1 = (const float*)d_in[32];
  const float* g2W2 = (const float*)d_in[33], *g2b2 = (const float*)d_in[34];
  const float* g2LW = (const float*)d_in[35], *g2Lb = (const float*)d_in[36];
  const float* rW1  = (const float*)d_in[37], *rb1  = (const float*)d_in[38];
  const float* rW2  = (const float*)d_in[39], *rb2  = (const float*)d_in[40];
  (void)in_sizes; (void)n_in; (void)out_size; (void)ws_size;

  char* ws = (char*)d_ws;
  size_t off = 0;
  auto alloc = [&](size_t bytes) -> char* {
    char* p = ws + off;
    off += (bytes + 255) & ~(size_t)255;
    return p;
  };
  float* tabs    = (float*)alloc((size_t)TAB_TOTAL * 4);
  // Activation region (76.8 MB): h2 [TN][64] at [0, 51.2M); h1 [TN][32]
  // at [51.2M, 76.8M). part scratch (NC*ENTCAP*8 = 32.03M) aliases the h2
  // region -- consumed by partition_to_csr before conv2 writes h2.
  char*  act   = alloc((size_t)TN * 64 * 4 + (size_t)TN * 32 * 4);  // 76.8 MB
  float* h2buf = (float*)act;
  float* h1buf = (float*)(act + (size_t)TN * 64 * 4);
  int2*  part  = (int2*)act;  // 32.03 MB <= 51.2 MB h2 region; dead before conv2
  __half* x0h  = (__half*)alloc((size_t)TN * 32 * 2);       // 12.8 MB fp16 shadow
  __half* x1h  = (__half*)alloc((size_t)TN * 64 * 2);       // 25.6 MB fp16 shadow
  int2*  colattr = (int2*) alloc((size_t)TE * 8);           // final CSR order
  int*   gcur    = (int*)  alloc((size_t)NC * 4);
  int*   rowptr  = (int*)  alloc((size_t)(TN + 1) * 4);
  int*   start_s = (int*)  alloc((size_t)(NBAT + 1) * 4);
  int*   start_g = (int*)  alloc((size_t)(NBAT + 1) * 4);
  float* psum    = (float*)alloc((size_t)2 * NBAT * 64 * 4);

  // build_tables also zeroes gcur + psum (memset dispatches folded in)
  build_tables<<<1, 256, 0, stream>>>(edW1, edb1, edW2, edb2, s2LW, s2Lb,
                                      g2LW, g2Lb, tabs, gcur, psum);

  // embed || partition || batch_bounds in one launch
  fused_front<<<ABLK + 782 + 782, 256, 0, stream>>>(
      names_s, names_g, idW1, idb1, idW2, idb2,
      ei_s, ei_s + NEDG, ea_s, ei_g, ei_g + NEDG, ea_g,
      bat_s, bat_g, tabs, x0h, gcur, part, start_s, start_g);
  partition_to_csr<<<NC, 256, 0, stream>>>(gcur, part, rowptr, colattr);

  conv1_dual<<<CONVBLK, 256, 0, stream>>>(x0h, rowptr, colattr, tabs, h1buf);
  mlp1_dual<<<TN / 64, 256, 0, stream>>>(h1buf,
                                         s1W1, s1b1, s1W2, s1b2,
                                         g1W1, g1b1, g1W2, g1b2, x1h);
  conv2_dual<<<CONVBLK, 256, 0, stream>>>(x1h, rowptr, colattr, tabs, h2buf);
  mlp2_pool_dual<<<TN / 64, 256, 0, stream>>>(h2buf,
                                              s2W1, s2b1, s2W2, s2b2,
                                              g2W1, g2b1, g2W2, g2b2,
                                              bat_s, bat_g, psum);
  regressor16<<<32, 256, 0, stream>>>(psum, start_s, start_g, depth,
                                      rW1, rb1, rW2, rb2, (float*)d_out);
}